// Round 11
// baseline (1100.534 us; speedup 1.0000x reference)
//
#include <hip/hip_runtime.h>
#include <hip/hip_bf16.h>
#include <math.h>

#define T 1024
#define NLAYER 4
#define NHEAD 16
#define HEAD 64
#define DIN 2048
#define MHEAD 32
#define DSTATE 64
#define FFH 4096
#define NWIN 4256
#define CCONV 2176
#define VOCABSZ 32000
#define NCHUNK 16
#define PKROWS 9472
#define PKN 9376

typedef unsigned short u16;
typedef __attribute__((ext_vector_type(8))) short s16x8;
typedef __attribute__((ext_vector_type(4))) float f32x4;

__device__ inline u16 f2bf(float f) {
  union { float f; unsigned u; } v; v.f = f;
  return (u16)((v.u + 0x7FFF + ((v.u >> 16) & 1)) >> 16);
}
__device__ inline float bf2f(u16 s) {
  union { unsigned u; float f; } v; v.u = ((unsigned)s) << 16;
  return v.f;
}
__device__ inline float sigf(float x) { return 1.f / (1.f + expf(-x)); }

__device__ inline void gload16(const void* g, void* l) {
  __builtin_amdgcn_global_load_lds(
      (__attribute__((address_space(1))) void*)(size_t)g,
      (__attribute__((address_space(3))) void*)(unsigned int)(size_t)l,
      16, 0, 0);
}

// T2 LDS swizzle for [rows][64]-bf16 tiles (128B row stride)
#define SWZ_SRC(lane) ((((lane) & 7) ^ ((lane) >> 3)) * 8)
#define SWZ_RD(kb, lk8, rsw) (((((kb) + (lk8)) >> 3) ^ (rsw)) << 3)

__device__ inline float block_sum(float v, float* sb) {
  #pragma unroll
  for (int o = 32; o; o >>= 1) v += __shfl_down(v, o);
  int w = threadIdx.x >> 6;
  if ((threadIdx.x & 63) == 0) sb[w] = v;
  __syncthreads();
  float s = sb[0] + sb[1] + sb[2] + sb[3];
  __syncthreads();
  return s;
}

// ---------------- weight conversion ----------------
__global__ __launch_bounds__(256) void k_cast(const float* __restrict__ s, u16* __restrict__ d) {
  size_t i = ((size_t)blockIdx.x * 256 + threadIdx.x) * 4;
  float4 v = *(const float4*)&s[i];
  u16 o[4] = {f2bf(v.x), f2bf(v.y), f2bf(v.z), f2bf(v.w)};
  *(uint2*)&d[i] = *(uint2*)o;
}

// generic transpose+cast f32 [K][N] -> bf16 [N][K]; z = layer
__global__ __launch_bounds__(256) void k_tcast(const float* __restrict__ src, size_t sstride,
                                               u16* __restrict__ dst, size_t dstride,
                                               int K, int N) {
  __shared__ float S[64][65];
  const float* sp = src + (size_t)blockIdx.z * sstride;
  u16* dp = dst + (size_t)blockIdx.z * dstride;
  int n0 = blockIdx.x * 64, k0 = blockIdx.y * 64;
  int tid = threadIdx.x;
  int tr = tid >> 4, tc = (tid & 15) * 4;
  #pragma unroll
  for (int it = 0; it < 4; ++it) {
    int r = tr + it * 16;
    int col = n0 + tc;
    float4 v;
    if (col + 3 < N) v = *(const float4*)&sp[(size_t)(k0 + r) * N + col];
    else {
      v.x = (col + 0 < N) ? sp[(size_t)(k0 + r) * N + col + 0] : 0.f;
      v.y = (col + 1 < N) ? sp[(size_t)(k0 + r) * N + col + 1] : 0.f;
      v.z = (col + 2 < N) ? sp[(size_t)(k0 + r) * N + col + 2] : 0.f;
      v.w = 0.f;
    }
    S[r][tc + 0] = v.x; S[r][tc + 1] = v.y; S[r][tc + 2] = v.z; S[r][tc + 3] = v.w;
  }
  __syncthreads();
  #pragma unroll
  for (int it = 0; it < 4; ++it) {
    int rn = tr + it * 16;
    if (n0 + rn >= N) continue;
    u16 o[4];
    o[0] = f2bf(S[tc + 0][rn]); o[1] = f2bf(S[tc + 1][rn]);
    o[2] = f2bf(S[tc + 2][rn]); o[3] = f2bf(S[tc + 3][rn]);
    *(uint2*)&dp[(size_t)(n0 + rn) * K + k0 + tc] = *(uint2*)o;
  }
}

// six 1024x1024 transposes in one dispatch; z = which*4 + layer
struct TC6 { const float* src[6]; u16* dst[6]; size_t dstride[6]; };
__global__ __launch_bounds__(256) void k_tcast6(TC6 tc) {
  __shared__ float S[64][65];
  int w = blockIdx.z >> 2, l = blockIdx.z & 3;
  const float* sp = tc.src[w] + (size_t)l * 1024 * 1024;
  u16* dp = tc.dst[w] + (size_t)l * tc.dstride[w];
  int n0 = blockIdx.x * 64, k0 = blockIdx.y * 64;
  int tid = threadIdx.x;
  int tr = tid >> 4, tcc = (tid & 15) * 4;
  #pragma unroll
  for (int it = 0; it < 4; ++it) {
    int r = tr + it * 16;
    float4 v = *(const float4*)&sp[(size_t)(k0 + r) * 1024 + n0 + tcc];
    S[r][tcc + 0] = v.x; S[r][tcc + 1] = v.y; S[r][tcc + 2] = v.z; S[r][tcc + 3] = v.w;
  }
  __syncthreads();
  #pragma unroll
  for (int it = 0; it < 4; ++it) {
    int rn = tr + it * 16;
    u16 o[4];
    o[0] = f2bf(S[tcc + 0][rn]); o[1] = f2bf(S[tcc + 1][rn]);
    o[2] = f2bf(S[tcc + 2][rn]); o[3] = f2bf(S[tcc + 3][rn]);
    *(uint2*)&dp[(size_t)(n0 + rn) * 1024 + k0 + tcc] = *(uint2*)o;
  }
}

// ---------------- embed + rmsnorm fused ----------------
__global__ __launch_bounds__(256) void k_embln(const int* x, const float* embed,
                                               const float* w, float* h, u16* out) {
  __shared__ float sb[8];
  int t = blockIdx.x, tid = threadIdx.x;
  int row = x[t];
  float4 v = *(const float4*)&embed[(size_t)row * 1024 + tid * 4];
  *(float4*)&h[(size_t)t * 1024 + tid * 4] = v;
  float ss = v.x * v.x + v.y * v.y + v.z * v.z + v.w * v.w;
  float tot = block_sum(ss, sb);
  float rn = rsqrtf(tot / 1024.f + 1e-6f);
  int c = tid * 4;
  u16 o[4] = {f2bf(v.x * rn * w[c + 0]), f2bf(v.y * rn * w[c + 1]),
              f2bf(v.z * rn * w[c + 2]), f2bf(v.w * rn * w[c + 3])};
  *(uint2*)&out[(size_t)t * 1024 + c] = *(uint2*)o;
}

// ---------------- GEMM: counted-vmcnt dbuf, TH threads, LDS <= 64KB ----------------
enum { EPI_F32 = 0, EPI_QKV = 1, EPI_GELU = 2 };

struct GOut {
  void* out;
  const float* aux;
  size_t zstride;
  float *r, *k, *v, *ld, *g, *zx;
};

template <int EPI, int BM, int BN, int TH>
__global__ __launch_bounds__(TH) void k_gemm2(const u16* __restrict__ A,
                                              const u16* __restrict__ Bt,
                                              int N, int K, int kLen, GOut go) {
  __shared__ __align__(16) u16 smem[2][BM + BN][64];
  constexpr int NW = TH / 64;
  constexpr int NWM = (NW == 8) ? 4 : 2;
  constexpr int NWN = NW / NWM;
  constexpr int FR = BM / NWM / 16, FC = BN / NWN / 16;
  constexpr int ROWS = BM + BN;
  constexpr int RPW = ROWS / NW;          // rows per wave per stage
  constexpr int LPS = RPW / 8;            // gload16 per thread per stage
  int tid = threadIdx.x, lane = tid & 63, wid = tid >> 6;
  int lid = blockIdx.y * gridDim.x + blockIdx.x;
  int nwg = gridDim.x * gridDim.y;
  int q = nwg >> 3, r8 = nwg & 7;
  int xcd = lid & 7, pos = lid >> 3;
  int wg = (xcd < r8) ? (xcd * (q + 1) + pos) : (r8 * (q + 1) + (xcd - r8) * q + pos);
  int m0 = (wg % gridDim.x) * BM, n0 = (wg / gridDim.x) * BN;
  int kOff = blockIdx.z * kLen;
  int wr = (wid / NWN) * (BM / NWM), wc = (wid % NWN) * (BN / NWN);
  int lr = lane & 15, lk8 = (lane >> 4) * 8;
  int rsw = lr & 7;
  int swc = SWZ_SRC(lane);
  int rA = lane >> 3;
  f32x4 acc[FR][FC] = {};

  auto STAGE = [&](int buf, int k0) {
    #pragma unroll
    for (int it = 0; it < LPS; ++it) {
      int rb = wid * RPW + it * 8;
      if (rb < BM)
        gload16(&A[(size_t)(m0 + rb + rA) * K + k0 + swc], &smem[buf][rb][0]);
      else
        gload16(&Bt[(size_t)(n0 + rb - BM + rA) * K + k0 + swc], &smem[buf][rb][0]);
    }
  };
  auto COMPUTE = [&](int buf) {
    #pragma unroll
    for (int kb = 0; kb < 64; kb += 32) {
      s16x8 af[FR], bf[FC];
      #pragma unroll
      for (int i = 0; i < FR; ++i)
        af[i] = *(const s16x8*)&smem[buf][wr + i * 16 + lr][SWZ_RD(kb, lk8, rsw)];
      #pragma unroll
      for (int j = 0; j < FC; ++j)
        bf[j] = *(const s16x8*)&smem[buf][BM + wc + j * 16 + lr][SWZ_RD(kb, lk8, rsw)];
      #pragma unroll
      for (int i = 0; i < FR; ++i)
        #pragma unroll
        for (int j = 0; j < FC; ++j)
          acc[i][j] = __builtin_amdgcn_mfma_f32_16x16x32_bf16(af[i], bf[j], acc[i][j], 0, 0, 0);
    }
  };

  int nt = kLen >> 6;
  STAGE(0, kOff);
  int cur = 0;
  for (int t = 0; t < nt; ++t) {
    if (t + 1 < nt) {
      STAGE(cur ^ 1, kOff + (t + 1) * 64);
      asm volatile("s_waitcnt vmcnt(%0)" :: "n"(LPS) : "memory");
    } else {
      asm volatile("s_waitcnt vmcnt(0)" ::: "memory");
    }
    __builtin_amdgcn_s_barrier();
    __builtin_amdgcn_sched_barrier(0);
    COMPUTE(cur);
    __builtin_amdgcn_s_barrier();
    cur ^= 1;
  }

  // ---- direct fragment-store epilogues (no LDS round-trip; keeps LDS = 64KB
  //      -> 2 blocks/CU under the observed ~128KB per-CU co-residency limit) ----
  #pragma unroll
  for (int i = 0; i < FR; ++i)
    #pragma unroll
    for (int j = 0; j < FC; ++j) {
      int row = m0 + wr + i * 16 + ((lane >> 4) << 2);
      int col = n0 + wc + j * 16 + lr;
      if (col >= N) continue;
      #pragma unroll
      for (int r_ = 0; r_ < 4; ++r_) {
        float v = acc[i][j][r_];
        size_t rr = (size_t)(row + r_);
        if constexpr (EPI == EPI_F32) {
          ((float*)go.out + (size_t)blockIdx.z * go.zstride)[rr * (size_t)N + col] = v;
        } else if constexpr (EPI == EPI_GELU) {
          ((u16*)go.out)[rr * (size_t)N + col] =
              f2bf(0.5f * v * (1.f + erff(v * 0.70710678118654752f)));
        } else if constexpr (EPI == EPI_QKV) {
          if (col < 1024)       go.r[rr * 1024 + col] = v;
          else if (col < 2048)  go.k[rr * 1024 + col - 1024] = v;
          else if (col < 3072)  go.v[rr * 1024 + col - 2048] = v;
          else if (col < 4096)  go.ld[rr * 1024 + col - 3072] = -__expf(v + go.aux[col - 3072]);
          else if (col < 5120)  go.g[rr * 1024 + col - 4096] = v * sigf(v);
          else                  go.zx[rr * 4256 + col - 5120] = v;
        }
      }
    }
}

// ---------------- dual GEMM: z=0: og@Wo -> out_rwkv ; z=1: ymn@Wom -> out_mam ------
struct DualArg {
  const u16 *A0, *A1, *B0, *B1;
  float *o0, *o1;
  int K0, K1;
};
__global__ __launch_bounds__(256) void k_dual(DualArg da) {
  __shared__ __align__(16) u16 smem[2][128][64];
  const u16* A  = blockIdx.z ? da.A1 : da.A0;
  const u16* Bt = blockIdx.z ? da.B1 : da.B0;
  float* out    = blockIdx.z ? da.o1 : da.o0;
  int K         = blockIdx.z ? da.K1 : da.K0;
  const int N = 1024;
  int tid = threadIdx.x, lane = tid & 63, wid = tid >> 6;
  int lid = blockIdx.y * gridDim.x + blockIdx.x;
  int nwg = gridDim.x * gridDim.y;
  int q = nwg >> 3, r8 = nwg & 7;
  int xcd = lid & 7, pos = lid >> 3;
  int wg = (xcd < r8) ? (xcd * (q + 1) + pos) : (r8 * (q + 1) + (xcd - r8) * q + pos);
  int m0 = (wg % gridDim.x) * 64, n0 = (wg / gridDim.x) * 64;
  int wr = (wid >> 1) * 32, wc = (wid & 1) * 32;
  int lr = lane & 15, lk8 = (lane >> 4) * 8;
  int rsw = lr & 7, swc = SWZ_SRC(lane), rA = lane >> 3;
  f32x4 acc[2][2] = {};
  auto STAGE = [&](int buf, int k0) {
    #pragma unroll
    for (int it = 0; it < 2; ++it) {
      int rb = wid * 16 + it * 8;
      gload16(&A[(size_t)(m0 + rb + rA) * K + k0 + swc], &smem[buf][rb][0]);
      gload16(&Bt[(size_t)(n0 + rb + rA) * K + k0 + swc], &smem[buf][64 + rb][0]);
    }
  };
  auto COMPUTE = [&](int buf) {
    #pragma unroll
    for (int kb = 0; kb < 64; kb += 32) {
      s16x8 af[2], bf[2];
      #pragma unroll
      for (int i = 0; i < 2; ++i)
        af[i] = *(const s16x8*)&smem[buf][wr + i * 16 + lr][SWZ_RD(kb, lk8, rsw)];
      #pragma unroll
      for (int j = 0; j < 2; ++j)
        bf[j] = *(const s16x8*)&smem[buf][64 + wc + j * 16 + lr][SWZ_RD(kb, lk8, rsw)];
      #pragma unroll
      for (int i = 0; i < 2; ++i)
        #pragma unroll
        for (int j = 0; j < 2; ++j)
          acc[i][j] = __builtin_amdgcn_mfma_f32_16x16x32_bf16(af[i], bf[j], acc[i][j], 0, 0, 0);
    }
  };
  int nt = K >> 6;
  STAGE(0, 0);
  int cur = 0;
  for (int t = 0; t < nt; ++t) {
    if (t + 1 < nt) {
      STAGE(cur ^ 1, (t + 1) * 64);
      asm volatile("s_waitcnt vmcnt(4)" ::: "memory");
    } else {
      asm volatile("s_waitcnt vmcnt(0)" ::: "memory");
    }
    __builtin_amdgcn_s_barrier();
    __builtin_amdgcn_sched_barrier(0);
    COMPUTE(cur);
    __builtin_amdgcn_s_barrier();
    cur ^= 1;
  }
  #pragma unroll
  for (int i = 0; i < 2; ++i)
    #pragma unroll
    for (int j = 0; j < 2; ++j) {
      int row = m0 + wr + i * 16 + ((lane >> 4) << 2);
      int col = n0 + wc + j * 16 + lr;
      #pragma unroll
      for (int r_ = 0; r_ < 4; ++r_)
        out[(size_t)(row + r_) * N + col] = acc[i][j][r_];
    }
}

// ---------------- causal depthwise conv (K=4) + silu, 4 ch/thread ----------------
__global__ __launch_bounds__(256) void k_conv(const float* __restrict__ zx,
                                              const float* __restrict__ cw,
                                              float* __restrict__ xc) {
  int c = (blockIdx.x * 256 + threadIdx.x) * 4;
  int t = blockIdx.y;
  if (c >= CCONV) return;
  float4 w0 = *(const float4*)&cw[(c + 0) * 4];
  float4 w1 = *(const float4*)&cw[(c + 1) * 4];
  float4 w2 = *(const float4*)&cw[(c + 2) * 4];
  float4 w3 = *(const float4*)&cw[(c + 3) * 4];
  float4 a = {0.f, 0.f, 0.f, 0.f};
  #pragma unroll
  for (int tap = 0; tap < 4; ++tap) {
    int tt = t - 3 + tap;
    if (tt < 0) continue;
    float4 z = *(const float4*)&zx[(size_t)tt * NWIN + 2048 + c];
    a.x += z.x * ((const float*)&w0)[tap];
    a.y += z.y * ((const float*)&w1)[tap];
    a.z += z.z * ((const float*)&w2)[tap];
    a.w += z.w * ((const float*)&w3)[tap];
  }
  a.x = a.x * sigf(a.x); a.y = a.y * sigf(a.y);
  a.z = a.z * sigf(a.z); a.w = a.w * sigf(a.w);
  *(float4*)&xc[(size_t)t * CCONV + c] = a;
}

// ---------------- dtla (y=0) + bc quarters (y=1..4), per chunk ----------------
__global__ __launch_bounds__(256) void k_dtbc(const float* __restrict__ zx,
                                              const float* __restrict__ xc,
                                              const float* __restrict__ dt_bias,
                                              const float* __restrict__ A_log,
                                              float* __restrict__ dtb, float* __restrict__ la,
                                              float* __restrict__ BC) {
  int c = blockIdx.x, tid = threadIdx.x;
  if (blockIdx.y == 0) {
    __shared__ float ldaS[64][33];
    #pragma unroll
    for (int it = 0; it < 8; ++it) {
      int e = it * 256 + tid;
      int i = e >> 5, j = e & 31;
      float x = zx[(size_t)(c * 64 + i) * NWIN + 4224 + j] + dt_bias[j];
      float sp = (x > 20.f) ? x : log1pf(expf(x));
      dtb[(size_t)(c * 64 + i) * 32 + j] = sp;
      ldaS[i][j] = -sp * expf(A_log[j]);
    }
    __syncthreads();
    if (tid < 32) {
      float g = 0.f;
      for (int i = 0; i < 64; ++i) {
        g += ldaS[i][tid];
        la[((size_t)c * 32 + tid) * 64 + i] = g;
      }
    }
  } else {
    __shared__ float Bc[64][65];
    __shared__ float Cc[16][65];
    int i0 = (blockIdx.y - 1) * 16;
    #pragma unroll
    for (int it = 0; it < 4; ++it) {
      int idx = it * 256 + tid;
      int r = idx >> 4, c4 = (idx & 15) * 4;
      float4 b4 = *(const float4*)&xc[(size_t)(c * 64 + r) * CCONV + 2048 + c4];
      Bc[r][c4] = b4.x; Bc[r][c4+1] = b4.y; Bc[r][c4+2] = b4.z; Bc[r][c4+3] = b4.w;
    }
    {
      int r = tid >> 4, c4 = (tid & 15) * 4;
      float4 cv = *(const float4*)&xc[(size_t)(c * 64 + i0 + r) * CCONV + 2112 + c4];
      Cc[r][c4] = cv.x; Cc[r][c4+1] = cv.y; Cc[r][c4+2] = cv.z; Cc[r][c4+3] = cv.w;
    }
    __syncthreads();
    int il = tid >> 4, sg = tid & 15;
    float acc[4] = {};
    for (int d = 0; d < 64; ++d) {
      float cv = Cc[il][d];
      #pragma unroll
      for (int j = 0; j < 4; ++j) acc[j] += Bc[sg * 4 + j][d] * cv;
    }
    #pragma unroll
    for (int j = 0; j < 4; ++j)
      BC[((size_t)c * 64 + i0 + il) * 64 + sg * 4 + j] = acc[j];
  }
}

// ---------------- heads1: rwkvA (y<16) || mambaU (y>=16) ----------------
union SmemH1 {
  struct { float rS[64][66], kS[64][66], gS[64][66]; u16 khS[64][64]; u16 vtS[64][72]; float uS[64]; } a;
  struct { u16 XT[64][72], BT[64][72]; float fS[64]; } b;
};
__global__ __launch_bounds__(256) void k_heads1(const float* __restrict__ rbuf,
                                                const float* __restrict__ kbuf,
                                                const float* __restrict__ ldbuf,
                                                const float* __restrict__ vbuf,
                                                const float* __restrict__ u,
                                                const float* __restrict__ xc,
                                                const float* __restrict__ la,
                                                const float* __restrict__ dtb,
                                                u16* __restrict__ rt, float* __restrict__ eL,
                                                u16* __restrict__ G, float* __restrict__ U,
                                                float* __restrict__ Um) {
  __shared__ SmemH1 sm;
  int c = blockIdx.x, tid = threadIdx.x;
  int lane = tid & 63, wid = tid >> 6;
  int lr = lane & 15, lk8 = (lane >> 4) * 8, rsw = lr & 7;
  int wr = (wid >> 1) * 32, wc = (wid & 1) * 32;
  if (blockIdx.y < 16) {
    int h = blockIdx.y;
    #pragma unroll
    for (int it = 0; it < 4; ++it) {
      int idx = it * 256 + tid;
      int i = idx >> 4, c4 = (idx & 15) * 4;
      size_t base = (size_t)(c * 64 + i) * 1024 + h * 64 + c4;
      float4 rv = *(const float4*)&rbuf[base];
      float4 kv = *(const float4*)&kbuf[base];
      float4 lv = *(const float4*)&ldbuf[base];
      float4 vv = *(const float4*)&vbuf[base];
      sm.a.rS[i][c4] = rv.x; sm.a.rS[i][c4+1] = rv.y; sm.a.rS[i][c4+2] = rv.z; sm.a.rS[i][c4+3] = rv.w;
      sm.a.kS[i][c4] = kv.x; sm.a.kS[i][c4+1] = kv.y; sm.a.kS[i][c4+2] = kv.z; sm.a.kS[i][c4+3] = kv.w;
      sm.a.gS[i][c4] = lv.x; sm.a.gS[i][c4+1] = lv.y; sm.a.gS[i][c4+2] = lv.z; sm.a.gS[i][c4+3] = lv.w;
      sm.a.vtS[c4 + 0][i] = f2bf(vv.x); sm.a.vtS[c4 + 1][i] = f2bf(vv.y);
      sm.a.vtS[c4 + 2][i] = f2bf(vv.z); sm.a.vtS[c4 + 3][i] = f2bf(vv.w);
    }
    if (tid < 64) sm.a.uS[tid] = u[h * 64 + tid];
    __syncthreads();
    if (tid < 64) {
      int k = tid;
      float g = 0.f;
      for (int i = 0; i < 64; ++i) {
        float ld = sm.a.gS[i][k];
        sm.a.gS[i][k] = g;
        rt[(size_t)(c * 64 + i) * 1024 + h * 64 + k] = f2bf(sm.a.rS[i][k] * __expf(g));
        g += ld;
      }
      float gL = g;
      eL[((size_t)c * 16 + h) * 64 + k] = __expf(gL);
      for (int i = 0; i < 64; ++i) {
        float gincl = (i < 63) ? sm.a.gS[i + 1][k] : gL;
        int col = (((i >> 3) ^ (k & 7)) << 3) | (i & 7);
        sm.a.khS[k][col] = f2bf(sm.a.kS[i][k] * __expf(fminf(gL - gincl, 0.f)));
      }
    }
    __syncthreads();
    {
      int i = tid & 63, sg = tid >> 6;
      float acc[16] = {};
      float accd = 0.f;
      for (int k = 0; k < 64; ++k) {
        float rv = sm.a.rS[i][k], gi = sm.a.gS[i][k];
        accd += rv * sm.a.uS[k] * sm.a.kS[i][k];
        #pragma unroll
        for (int j = 0; j < 16; ++j) {
          int s = sg * 16 + j;
          int sp1 = (s < 63) ? s + 1 : 63;
          acc[j] += rv * sm.a.kS[s][k] * __expf(fminf(gi - sm.a.gS[sp1][k], 0.f));
        }
      }
      #pragma unroll
      for (int j = 0; j < 16; ++j) {
        int s = sg * 16 + j;
        float v = (s < i) ? acc[j] : ((s == i) ? accd : 0.f);
        G[(((size_t)c * 16 + h) * 64 + i) * 64 + s] = f2bf(v);
      }
    }
    {
      size_t gb = ((size_t)c * 16 + h) * 64;
      f32x4 acc2[2][2] = {};
      #pragma unroll
      for (int kb = 0; kb < 64; kb += 32) {
        s16x8 a[2], b[2];
        #pragma unroll
        for (int i_ = 0; i_ < 2; ++i_)
          a[i_] = *(const s16x8*)&sm.a.khS[wr + i_ * 16 + lr][SWZ_RD(kb, lk8, rsw)];
        #pragma unroll
        for (int j_ = 0; j_ < 2; ++j_)
          b[j_] = *(const s16x8*)&sm.a.vtS[wc + j_ * 16 + lr][kb + lk8];
        #pragma unroll
        for (int i_ = 0; i_ < 2; ++i_)
          #pragma unroll
          for (int j_ = 0; j_ < 2; ++j_)
            acc2[i_][j_] = __builtin_amdgcn_mfma_f32_16x16x32_bf16(a[i_], b[j_], acc2[i_][j_], 0, 0, 0);
      }
      #pragma unroll
      for (int i_ = 0; i_ < 2; ++i_)
        #pragma unroll
        for (int j_ = 0; j_ < 2; ++j_) {
          int row = wr + i_ * 16 + ((lane >> 4) << 2);
          int col = wc + j_ * 16 + lr;
          #pragma unroll
          for (int r_ = 0; r_ < 4; ++r_)
            U[(gb + row + r_) * 64 + col] = acc2[i_][j_][r_];
        }
    }
  } else {
    int h = blockIdx.y - 16;
    size_t lb = ((size_t)c * 32 + h) * 64;
    if (tid < 64) {
      float la63 = la[lb + 63];
      sm.b.fS[tid] = dtb[(size_t)(c * 64 + tid) * 32 + h] * __expf(fminf(la63 - la[lb + tid], 0.f));
    }
    __syncthreads();
    #pragma unroll
    for (int it = 0; it < 4; ++it) {
      int idx = it * 256 + tid;
      int t = idx >> 4, p4 = (idx & 15) * 4;
      float f = sm.b.fS[t];
      float4 xv = *(const float4*)&xc[(size_t)(c * 64 + t) * CCONV + h * 64 + p4];
      sm.b.XT[p4 + 0][t] = f2bf(f * xv.x); sm.b.XT[p4 + 1][t] = f2bf(f * xv.y);
      sm.b.XT[p4 + 2][t] = f2bf(f * xv.z); sm.b.XT[p4 + 3][t] = f2bf(f * xv.w);
      float4 bv = *(const float4*)&xc[(size_t)(c * 64 + t) * CCONV + 2048 + p4];
      sm.b.BT[p4 + 0][t] = f2bf(bv.x); sm.b.BT[p4 + 1][t] = f2bf(bv.y);
      sm.b.BT[p4 + 2][t] = f2bf(bv.z); sm.b.BT[p4 + 3][t] = f2bf(bv.w);
    }
    __syncthreads();
    f32x4 acc[2][2] = {};
    #pragma unroll
    for (int kb = 0; kb < 64; kb += 32) {
      s16x8 a[2], b[2];
      #pragma unroll
      for (int i = 0; i < 2; ++i) a[i] = *(const s16x8*)&sm.b.XT[wr + i * 16 + lr][kb + lk8];
      #pragma unroll
      for (int j = 0; j < 2; ++j) b[j] = *(const s16x8*)&sm.b.BT[wc + j * 16 + lr][kb + lk8];
      #pragma unroll
      for (int i = 0; i < 2; ++i)
        #pragma unroll
        for (int j = 0; j < 2; ++j)
          acc[i][j] = __builtin_amdgcn_mfma_f32_16x16x32_bf16(a[i], b[j], acc[i][j], 0, 0, 0);
    }
    #pragma unroll
    for (int i = 0; i < 2; ++i)
      #pragma unroll
      for (int j = 0; j < 2; ++j) {
        int row = wr + i * 16 + ((lane >> 4) << 2);
        int col = wc + j * 16 + lr;
        #pragma unroll
        for (int r_ = 0; r_ < 4; ++r_)
          Um[(lb + row + r_) * 64 + col] = acc[i][j][r_];
      }
  }
}

// ---------------- scan2: rwkv (x<16) || mamba (x>=16) ----------------
__global__ __launch_bounds__(256) void k_scan2(const float* __restrict__ Urw,
                                               const float* __restrict__ eL,
                                               u16* __restrict__ Sall,
                                               const float* __restrict__ Um,
                                               const float* __restrict__ la,
                                               u16* __restrict__ hall) {
  int tid = threadIdx.x;
  if (blockIdx.x < 16) {
    int h = blockIdx.x;
    int k = tid >> 2, v0 = blockIdx.y * 16 + (tid & 3) * 4;
    float S[4] = {};
    for (int c = 0; c < 16; ++c) {
      size_t gb = ((size_t)c * 16 + h) * 64;
      u16 tmp[4] = {f2bf(S[0]), f2bf(S[1]), f2bf(S[2]), f2bf(S[3])};
      *(uint2*)&Sall[(gb + k) * 64 + v0] = *(uint2*)&tmp[0];
      float e = eL[gb + k];
      float4 uv = *(const float4*)&Urw[(gb + k) * 64 + v0];
      S[0] = e * S[0] + uv.x; S[1] = e * S[1] + uv.y;
      S[2] = e * S[2] + uv.z; S[3] = e * S[3] + uv.w;
    }
  } else {
    int h = blockIdx.x - 16;
    int p = tid >> 2, s0 = blockIdx.y * 16 + (tid & 3) * 4;
    float S[4] = {};
    for (int c = 0; c < 16; ++c) {
      size_t lb = ((size_t)c * 32 + h) * 64;
      u16 tmp[4] = {f2bf(S[0]), f2bf(S[1]), f2bf(S[2]), f2bf(S[3])};
      *(uint2*)&hall[(lb + p) * 64 + s0] = *(uint2*)&tmp[0];
      float e = __expf(la[lb + 63]);
      float4 uv = *(const float4*)&Um[(lb + p) * 64 + s0];
      S[0] = e * S[0] + uv.x; S[1] = e * S[1] + uv.y;
      S[2] = e * S[2] + uv.z; S[3] = e * S[3] + uv.w;
    }
  }
}

// ---------------- heads2: rwkvO (y<16) || mambaY w/ inline M (y>=16) ----------------
union SmemH2 {
  struct { u16 rtS[64][64], GS[64][64], StS[64][72], vtS[64][72]; } a;
  struct { u16 MS[64][64], hS[64][64], CtS[64][72], XT2[64][72]; float laS[64], dtbS[64], eS[64]; } b;
};
__global__ __launch_bounds__(256) void k_heads2(const u16* __restrict__ rt,
                                                const u16* __restrict__ Gb,
                                                const u16* __restrict__ Sall,
                                                const float* __restrict__ vbuf,
                                                const float* __restrict__ gbuf,
                                                u16* __restrict__ og,
                                                const u16* __restrict__ hall,
                                                const float* __restrict__ xc,
                                                const float* __restrict__ la,
                                                const float* __restrict__ dtb,
                                                const float* __restrict__ BC,
                                                float* __restrict__ ymb) {
  __shared__ SmemH2 sm;
  int c = blockIdx.x, tid = threadIdx.x;
  int lane = tid & 63, wid = tid >> 6;
  int lr = lane & 15, lk8 = (lane >> 4) * 8;
  int rsw = lr & 7, swc = SWZ_SRC(lane);
  int wr = (wid >> 1) * 32, wc = (wid & 1) * 32;
  if (blockIdx.y < 16) {
    int h = blockIdx.y;
    size_t gb = ((size_t)c * 16 + h) * 64;
    #pragma unroll
    for (int it = 0; it < 2; ++it) {
      int rb = wid * 16 + it * 8;
      int r = rb + (lane >> 3);
      gload16(&rt[(size_t)(c * 64 + r) * 1024 + h * 64 + swc], &sm.a.rtS[rb][0]);
      gload16(&Gb[(gb + r) * 64 + swc], &sm.a.GS[rb][0]);
    }
    #pragma unroll
    for (int it = 0; it < 2; ++it) {
      int idx = it * 256 + tid;
      int k = idx >> 3, c8 = (idx & 7) * 8;
      uint4 ld = *(const uint4*)&Sall[(gb + k) * 64 + c8];
      const u16* pv = (const u16*)&ld;
      #pragma unroll
      for (int jj = 0; jj < 8; ++jj) sm.a.StS[c8 + jj][k] = pv[jj];
    }
    #pragma unroll
    for (int it = 0; it < 4; ++it) {
      int idx = it * 256 + tid;
      int s = idx >> 4, v4 = (idx & 15) * 4;
      float4 vv = *(const float4*)&vbuf[(size_t)(c * 64 + s) * 1024 + h * 64 + v4];
      sm.a.vtS[v4 + 0][s] = f2bf(vv.x); sm.a.vtS[v4 + 1][s] = f2bf(vv.y);
      sm.a.vtS[v4 + 2][s] = f2bf(vv.z); sm.a.vtS[v4 + 3][s] = f2bf(vv.w);
    }
    __syncthreads();
    f32x4 acc[2][2] = {};
    #pragma unroll
    for (int kb = 0; kb < 64; kb += 32) {
      s16x8 aR[2], aG[2], bS[2], bV[2];
      #pragma unroll
      for (int i = 0; i < 2; ++i) {
        aR[i] = *(const s16x8*)&sm.a.rtS[wr + i * 16 + lr][SWZ_RD(kb, lk8, rsw)];
        aG[i] = *(const s16x8*)&sm.a.GS[wr + i * 16 + lr][SWZ_RD(kb, lk8, rsw)];
      }
      #pragma unroll
      for (int j = 0; j < 2; ++j) {
        bS[j] = *(const s16x8*)&sm.a.StS[wc + j * 16 + lr][kb + lk8];
        bV[j] = *(const s16x8*)&sm.a.vtS[wc + j * 16 + lr][kb + lk8];
      }
      #pragma unroll
      for (int i = 0; i < 2; ++i)
        #pragma unroll
        for (int j = 0; j < 2; ++j) {
          acc[i][j] = __builtin_amdgcn_mfma_f32_16x16x32_bf16(aR[i], bS[j], acc[i][j], 0, 0, 0);
          acc[i][j] = __builtin_amdgcn_mfma_f32_16x16x32_bf16(aG[i], bV[j], acc[i][j], 0, 0, 0);
        }
    }
    #pragma unroll
    for (int i = 0; i < 2; ++i)
      #pragma unroll
      for (int j = 0; j < 2; ++j) {
        int row = c * 64 + wr + i * 16 + ((lane >> 4) << 2);
        int col = h * 64 + wc + j * 16 + lr;
        #pragma unroll
        for (int r_ = 0; r_ < 4; ++r_) {
          size_t idx = (size_t)(row + r_) * 1024 + col;
          og[idx] = f2bf(acc[i][j][r_] * gbuf[idx]);
        }
      }
  } else {
    int h = blockIdx.y - 16;
    size_t lb = ((size_t)c * 32 + h) * 64;
    if (tid < 64) {
      float lv = la[lb + tid];
      sm.b.laS[tid] = lv;
      sm.b.eS[tid] = __expf(lv);
      sm.b.dtbS[tid] = dtb[(size_t)(c * 64 + tid) * 32 + h];
    }
    #pragma unroll
    for (int it = 0; it < 2; ++it) {
      int rb = wid * 16 + it * 8;
      int r = rb + (lane >> 3);
      gload16(&hall[(lb + r) * 64 + swc], &sm.b.hS[rb][0]);
    }
    __syncthreads();
    #pragma unroll
    for (int it = 0; it < 4; ++it) {
      int idx = it * 256 + tid;
      int i = idx >> 4, s4 = (idx & 15) * 4;
      float lai = sm.b.laS[i];
      float4 bc4 = *(const float4*)&BC[((size_t)c * 64 + i) * 64 + s4];
      u16 mo[4];
      #pragma unroll
      for (int j = 0; j < 4; ++j) {
        int s = s4 + j;
        float bcv = (j == 0) ? bc4.x : (j == 1) ? bc4.y : (j == 2) ? bc4.z : bc4.w;
        float v = 0.f;
        if (s <= i)
          v = __expf(fminf(lai - sm.b.laS[s], 0.f)) * sm.b.dtbS[s] * bcv;
        mo[j] = f2bf(v);
      }
      *(uint2*)&sm.b.MS[i][(((s4 >> 3) ^ (i & 7)) << 3) | (s4 & 7)] = *(uint2*)mo;
      float ei = sm.b.eS[i];
      float4 cv = *(const float4*)&xc[(size_t)(c * 64 + i) * CCONV + 2112 + s4];
      sm.b.CtS[i][s4 + 0] = f2bf(ei * cv.x); sm.b.CtS[i][s4 + 1] = f2bf(ei * cv.y);
      sm.b.CtS[i][s4 + 2] = f2bf(ei * cv.z); sm.b.CtS[i][s4 + 3] = f2bf(ei * cv.w);
      float4 xv = *(const float4*)&xc[(size_t)(c * 64 + i) * CCONV + h * 64 + s4];
      sm.b.XT2[s4 + 0][i] = f2bf(xv.x); sm.b.XT2[s4 + 1][i] = f2bf(xv.y);
      sm.b.XT2[s4 + 2][i] = f2bf(xv.z); sm.b.XT2[s4 + 3][i] = f2bf(xv.w);
    }
    __syncthreads();
    f32x4 acc[2][2] = {};
    #pragma unroll
    for (int kb = 0; kb < 64; kb += 32) {
      s16x8 aM[2], aC[2], bX[2], bH[2];
      #pragma unroll
      for (int i = 0; i < 2; ++i) {
        aM[i] = *(const s16x8*)&sm.b.MS[wr + i * 16 + lr][SWZ_RD(kb, lk8, rsw)];
        aC[i] = *(const s16x8*)&sm.b.CtS[wr + i * 16 + lr][kb + lk8];
      }
      #pragma unroll
      for (int j = 0; j < 2; ++j) {
        bX[j] = *(const s16x8*)&sm.b.XT2[wc + j * 16 + lr][kb + lk8];
        bH[j] = *(const s16x8*)&sm.b.hS[wc + j * 16 + lr][SWZ_RD(kb, lk8, rsw)];
      }
      #pragma unroll
      for (int i = 0; i < 2; ++i)
        #pragma unroll
        for (int j = 0; j < 2; ++j) {
          acc[i][j] = __builtin_amdgcn_mfma_f32_16x16x32_bf16(aM[i], bX[j], acc[i][j], 0, 0, 0);
          acc[i][j] = __builtin_amdgcn_mfma_f32_16x16x32_bf16(aC[i], bH[j], acc[i][j], 0, 0, 0);
        }
    }
    #pragma unroll
    for (int i = 0; i < 2; ++i)
      #pragma unroll
      for (int j = 0; j < 2; ++j) {
        int row = c * 64 + wr + i * 16 + ((lane >> 4) << 2);
        int col = h * 64 + wc + j * 16 + lr;
        #pragma unroll
        for (int r_ = 0; r_ < 4; ++r_)
          ymb[(size_t)(row + r_) * 2048 + col] = acc[i][j][r_];
      }
  }
}

// ---------------- ym: +Dskip*x, *silu(z), rmsnorm(2048) -> bf16 ----------------
__global__ __launch_bounds__(256) void k_ymn(const float* ymb, const float* xc,
                                             const float* zx, const float* Dsk,
                                             const float* mnw, u16* out) {
  __shared__ float sb[8];
  int t = blockIdx.x, tid = threadIdx.x;
  float vals[8];
  float ss = 0.f;
  #pragma unroll
  for (int j = 0; j < 8; ++j) {
    int cidx = j * 256 + tid;
    float yv = ymb[(size_t)t * 2048 + cidx] + Dsk[cidx >> 6] * xc[(size_t)t * CCONV + cidx];
    float zv = zx[(size_t)t * NWIN + cidx];
    float val = yv * zv * sigf(zv);
    vals[j] = val;
    ss += val * val;
  }
  float tot = block_sum(ss, sb);
  float rn = rsqrtf(tot / 2048.f + 1e-6f);
  #pragma unroll
  for (int j = 0; j < 8; ++j) {
    int cidx = j * 256 + tid;
    out[(size_t)t * 2048 + cidx] = f2bf(vals[j] * rn * mnw[cidx]);
  }
}

// ---------------- gate + residual + ffn rmsnorm (fused) ----------------
__global__ __launch_bounds__(256) void k_gateln(const float* rw, const float* mb,
                                                const float* gw, const float* gb,
                                                float* h, const float* w, u16* nx) {
  __shared__ float sb[8];
  int t = blockIdx.x, tid = threadIdx.x;
  float s = 0.f;
  #pragma unroll
  for (int j = 0; j < 4; ++j) {
    int d = j * 256 + tid;
    s += rw[(size_t)t * 1024 + d] * gw[d] + mb[(size_t)t * 1024 + d] * gw[1024 + d];
  }
  float tot = block_sum(s, sb);
  float gate = sigf(tot + gb[0]);
  float hv[4], ss = 0.f;
  #pragma unroll
  for (int j = 0; j < 4; ++j) {
    int d = j * 256 + tid;
    float v = h[(size_t)t * 1024 + d] + gate * rw[(size_t)t * 1024 + d] +
              (1.f - gate) * mb[(size_t)t * 1024 + d];
    h[(size_t)t * 1024 + d] = v;
    hv[j] = v;
    ss += v * v;
  }
  float tot2 = block_sum(ss, sb);
  float rn = rsqrtf(tot2 / 1024.f + 1e-6f);
  #pragma unroll
  for (int j = 0; j < 4; ++j) {
    int d = j * 256 + tid;
    nx[(size_t)t * 1024 + d] = f2bf(hv[j] * rn * w[d]);
  }
}

// ---------------- W2 splitK reduce + h += + next rmsnorm (fused) ----------------
__global__ __launch_bounds__(256) void k_redln(const float* __restrict__ part,
                                               float* __restrict__ h,
                                               const float* __restrict__ w,
                                               u16* __restrict__ nx) {
  __shared__ float sb[8];
  int t = blockIdx.x, tid = threadIdx.x;
  size_t base = (size_t)t * 1024 + tid * 4;
  float4 s = *(const float4*)&part[base];
  #pragma unroll
  for (int p = 1; p < 4; ++p) {
    float4 v = *(const float4*)&part[(size_t)p * 1024 * 1024 + base];
    s.x += v.x; s.y += v.y; s.z += v.z; s.w += v.w;
  }
  float4 d = *(const float4*)&h[base];
  s.x += d.x; s.y += d.y; s.z += d.z; s.w += d.w;
  *(float4*)&h[base] = s;
  float ss = s.x * s.x + s.y * s.y + s.z * s.z + s.w * s.w;
  float tot = block_sum(ss, sb);
  float rn = rsqrtf(tot / 1024.f + 1e-6f);
  int c = tid * 4;
  u16 o[4] = {f2bf(s.x * rn * w[c + 0]), f2bf(s.y * rn * w[c + 1]),
              f2bf(s.z * rn * w[c + 2]), f2bf(s.w * rn * w[c + 3])};
  *(uint2*)&nx[(size_t)t * 1024 + c] = *(uint2*)o;
}

// =======================================================================
extern "C" void kernel_launch(void* const* d_in, const int* in_sizes, int n_in,
                              void* d_out, int out_size, void* d_ws, size_t ws_size,
                              hipStream_t stream) {
  const int*   x       = (const int*)d_in[0];
  const float* embed   = (const float*)d_in[1];
  const float* ln_w    = (const float*)d_in[2];
  const float* Wr      = (const float*)d_in[3];
  const float* Wk      = (const float*)d_in[4];
  const float* Wv      = (const float*)d_in[5];
  const float* Ww      = (const float*)d_in[6];
  const float* w_bias  = (const float*)d_in[7];
  const float* u       = (const float*)d_in[8];
  const float* Wg      = (const float*)d_in[9];
  const float* Wo      = (const float*)d_in[10];
  const float* Win     = (const float*)d_in[11];
  const float* conv_w  = (const float*)d_in[12];
  const float* dt_bias = (const float*)d_in[13];
  const float* A_log   = (const float*)d_in[14];
  const float* Dskip   = (const float*)d_in[15];
  const float* mnorm_w = (const float*)d_in[16];
  const float* Wout_m  = (const float*)d_in[17];
  const float* gate_w  = (const float*)d_in[18];
  const float* gate_b  = (const float*)d_in[19];
  const float* ffn_ln  = (const float*)d_in[20];
  const float* W1      = (const float*)d_in[21];
  const float* W2      = (const float*)d_in[22];
  const float* ln_out  = (const float*)d_in[23];

  char* p = (char*)d_ws;
  auto alloc = [&](size_t bytes) {
    char* r = p;
    p += (bytes + 255) & ~(size_t)255;
    return r;
  };
  u16* embB = (u16*)alloc((size_t)VOCABSZ * 1024 * 2);
  u16* Wpk  = (u16*)alloc((size_t)NLAYER * PKROWS * 1024 * 2);
  u16* WoT  = (u16*)alloc((size_t)NLAYER * 1024 * 1024 * 2);
  u16* WomT = (u16*)alloc((size_t)NLAYER * 1024 * 2048 * 2);
  u16* W1T  = (u16*)alloc((size_t)NLAYER * 4096 * 1024 * 2);
  u16* W2T  = (u16*)alloc((size_t)NLAYER * 1024 * 4096 * 2);
  float* h        = (float*)alloc((size_t)T * 1024 * 4);
  u16*   nx       = (u16*)alloc((size_t)T * 1024 * 2);
  float* rbuf     = (float*)alloc((size_t)T * 1024 * 4);
  float* kbuf     = (float*)alloc((size_t)T * 1024 * 4);
  float* vbuf     = (float*)alloc((size_t)T * 1024 * 4);
  float* ldbuf    = (float*)alloc((size_t)T * 1024 * 4);
  float* gbuf     = (float*)alloc((size_t)T * 1024 * 4);
  float* zx       = (float*)alloc((size_t)T * NWIN * 4);
  u16*   rt       = (u16*)alloc((size_t)T * 1024 * 2);
  float* eL       = (float*)alloc((size_t)NCHUNK * 16 * 64 * 4);
  u16*   Gb       = (u16*)alloc((size_t)NCHUNK * 16 * 64 * 64 * 2);
  float* Urw      = (float*)alloc((size_t)NCHUNK * 16 * 64 * 64 * 4);
  u16*   Sall     = (u16*)alloc((size_t)NCHUNK * 16 * 64 * 64 * 2);
  u16*   og       = (u16*)alloc((size_t)T * 1024 * 2);
  float* out_rwkv = (float*)alloc((size_t)T * 1024 * 4);
  float* xc       = (float*)alloc((size_t)T * CCONV * 4);
  float* dtb      = (float*)alloc((size_t)T * 32 * 4);
  float* la       = (float*)alloc((size_t)NCHUNK * 32 * 64 * 4);
  float* BC       = (float*)alloc((size_t)NCHUNK * 64 * 64 * 4);
  float* Um       = (float*)alloc((size_t)NCHUNK * 32 * 64 * 64 * 4);
  u16*   hall     = (u16*)alloc((size_t)NCHUNK * 32 * 64 * 64 * 2);
  float* ymb      = (float*)alloc((size_t)T * 2048 * 4);
  u16*   ymn      = (u16*)alloc((size_t)T * 2048 * 2);
  float* out_mam  = (float*)alloc((size_t)T * 1024 * 4);
  u16*   ffa      = (u16*)alloc((size_t)T * FFH * 2);
  float* part     = (float*)alloc((size_t)4 * 1024 * 1024 * 4);

  const size_t PKS = (size_t)PKROWS * 1024;

  // ---- weight conversion ----
  k_cast<<<VOCABSZ * 1024 / 1024, 256, 0, stream>>>(embed, embB);
  {
    TC6 tc;
    tc.src[0] = Wr; tc.src[1] = Wk; tc.src[2] = Wv; tc.src[3] = Ww; tc.src[4] = Wg; tc.src[5] = Wo;
    tc.dst[0] = Wpk;               tc.dstride[0] = PKS;
    tc.dst[1] = Wpk + 1024 * 1024; tc.dstride[1] = PKS;
    tc.dst[2] = Wpk + 2048 * 1024; tc.dstride[2] = PKS;
    tc.dst[3] = Wpk + 3072 * 1024; tc.dstride[3] = PKS;
    tc.dst[4] = Wpk + 4096 * 1024; tc.dstride[4] = PKS;
    tc.dst[5] = WoT;               tc.dstride[5] = (size_t)1024 * 1024;
    k_tcast6<<<dim3(16, 16, 24), 256, 0, stream>>>(tc);
  }
  k_tcast<<<dim3(67, 16, 4), 256, 0, stream>>>(Win, (size_t)1024 * NWIN, Wpk + (size_t)5120 * 1024, PKS, 1024, NWIN);
  k_tcast<<<dim3(16, 32, 4), 256, 0, stream>>>(Wout_m, (size_t)2048 * 1024, WomT, (size_t)1024 * 2048, 2048, 1024);
  k_tcast<<<dim3(64, 16, 4), 256, 0, stream>>>(W1, (size_t)1024 * 4096, W1T, (size_t)4096 * 1024, 1024, 4096);
  k_tcast<<<dim3(16, 64, 4), 256, 0, stream>>>(W2, (size_t)4096 * 1024, W2T, (size_t)1024 * 4096, 4096, 1024);

  k_embln<<<1024, 256, 0, stream>>>(x, embed, ln_w, h, nx);

  for (int l = 0; l < NLAYER; ++l) {
    {
      GOut go = {};
      go.r = rbuf; go.k = kbuf; go.v = vbuf; go.ld = ldbuf; go.g = gbuf; go.zx = zx;
      go.aux = w_bias + l * 1024;
      k_gemm2<EPI_QKV, 128, 128, 256><<<dim3(8, 74), 256, 0, stream>>>(nx, Wpk + (size_t)l * PKS, PKN, 1024, 1024, go);
    }
    k_conv<<<dim3(3, 1024), 256, 0, stream>>>(zx, conv_w + (size_t)l * CCONV * 4, xc);
    k_dtbc<<<dim3(16, 5), 256, 0, stream>>>(zx, xc, dt_bias + l * 32, A_log + l * 32, dtb, la, BC);
    k_heads1<<<dim3(16, 48), 256, 0, stream>>>(rbuf, kbuf, ldbuf, vbuf, u + (size_t)l * 1024,
                                               xc, la, dtb, rt, eL, Gb, Urw, Um);
    k_scan2<<<dim3(48, 4), 256, 0, stream>>>(Urw, eL, Sall, Um, la, hall);
    k_heads2<<<dim3(16, 48), 256, 0, stream>>>(rt, Gb, Sall, vbuf, gbuf, og,
                                               hall, xc, la, dtb, BC, ymb);
    k_ymn<<<1024, 256, 0, stream>>>(ymb, xc, zx, Dskip + l * 32, mnorm_w + (size_t)l * 2048, ymn);
    {
      DualArg da;
      da.A0 = og;  da.B0 = WoT + (size_t)l * 1024 * 1024;  da.o0 = out_rwkv; da.K0 = 1024;
      da.A1 = ymn; da.B1 = WomT + (size_t)l * 1024 * 2048; da.o1 = out_mam;  da.K1 = 2048;
      k_dual<<<dim3(16, 16, 2), 256, 0, stream>>>(da);
    }
    k_gateln<<<1024, 256, 0, stream>>>(out_rwkv, out_mam, gate_w + (size_t)l * 2048,
                                       gate_b + l, h, ffn_ln + l * 1024, nx);
    {
      GOut go = {}; go.out = ffa;
      k_gemm2<EPI_GELU, 128, 128, 256><<<dim3(8, 32), 256, 0, stream>>>(nx, W1T + (size_t)l * 4096 * 1024, 4096, 1024, 1024, go);
    }
    {
      GOut go = {}; go.out = part; go.zstride = (size_t)1024 * 1024;
      k_gemm2<EPI_F32, 64, 64, 256><<<dim3(16, 16, 4), 256, 0, stream>>>(ffa, W2T + (size_t)l * 1024 * 4096, 1024, 4096, 1024, go);
    }
    k_redln<<<1024, 256, 0, stream>>>(part, h,
                                      (l < NLAYER - 1) ? (ln_w + (l + 1) * 1024) : ln_out, nx);
  }

  {
    GOut go = {}; go.out = d_out;
    k_gemm2<EPI_F32, 128, 128, 512><<<dim3(8, 250), 512, 0, stream>>>(nx, embB, VOCABSZ, 1024, 1024, go);
  }
}

// Round 12
// 1029.386 us; speedup vs baseline: 1.0691x; 1.0691x over previous
//
#include <hip/hip_runtime.h>
#include <hip/hip_bf16.h>
#include <math.h>

#define T 1024
#define NLAYER 4
#define NHEAD 16
#define HEAD 64
#define DIN 2048
#define MHEAD 32
#define DSTATE 64
#define FFH 4096
#define NWIN 4256
#define CCONV 2176
#define VOCABSZ 32000
#define NCHUNK 16
#define PKROWS 9472
#define PKN 9376

typedef unsigned short u16;
typedef __attribute__((ext_vector_type(8))) short s16x8;
typedef __attribute__((ext_vector_type(4))) float f32x4;

__device__ inline u16 f2bf(float f) {
  union { float f; unsigned u; } v; v.f = f;
  return (u16)((v.u + 0x7FFF + ((v.u >> 16) & 1)) >> 16);
}
__device__ inline float bf2f(u16 s) {
  union { unsigned u; float f; } v; v.u = ((unsigned)s) << 16;
  return v.f;
}
__device__ inline float sigf(float x) { return 1.f / (1.f + expf(-x)); }

__device__ inline void gload16(const void* g, void* l) {
  __builtin_amdgcn_global_load_lds(
      (__attribute__((address_space(1))) void*)(size_t)g,
      (__attribute__((address_space(3))) void*)(unsigned int)(size_t)l,
      16, 0, 0);
}

// T2 LDS swizzle for [rows][64]-bf16 tiles (128B row stride)
#define SWZ_SRC(lane) ((((lane) & 7) ^ ((lane) >> 3)) * 8)
#define SWZ_RD(kb, lk8, rsw) (((((kb) + (lk8)) >> 3) ^ (rsw)) << 3)

__device__ inline float block_sum(float v, float* sb) {
  #pragma unroll
  for (int o = 32; o; o >>= 1) v += __shfl_down(v, o);
  int w = threadIdx.x >> 6;
  if ((threadIdx.x & 63) == 0) sb[w] = v;
  __syncthreads();
  float s = sb[0] + sb[1] + sb[2] + sb[3];
  __syncthreads();
  return s;
}

// ---------------- weight conversion ----------------
__global__ __launch_bounds__(256) void k_cast(const float* __restrict__ s, u16* __restrict__ d) {
  size_t i = ((size_t)blockIdx.x * 256 + threadIdx.x) * 4;
  float4 v = *(const float4*)&s[i];
  u16 o[4] = {f2bf(v.x), f2bf(v.y), f2bf(v.z), f2bf(v.w)};
  *(uint2*)&d[i] = *(uint2*)o;
}

// generic transpose+cast f32 [K][N] -> bf16 [N][K]; z = layer
__global__ __launch_bounds__(256) void k_tcast(const float* __restrict__ src, size_t sstride,
                                               u16* __restrict__ dst, size_t dstride,
                                               int K, int N) {
  __shared__ float S[64][65];
  const float* sp = src + (size_t)blockIdx.z * sstride;
  u16* dp = dst + (size_t)blockIdx.z * dstride;
  int n0 = blockIdx.x * 64, k0 = blockIdx.y * 64;
  int tid = threadIdx.x;
  int tr = tid >> 4, tc = (tid & 15) * 4;
  #pragma unroll
  for (int it = 0; it < 4; ++it) {
    int r = tr + it * 16;
    int col = n0 + tc;
    float4 v;
    if (col + 3 < N) v = *(const float4*)&sp[(size_t)(k0 + r) * N + col];
    else {
      v.x = (col + 0 < N) ? sp[(size_t)(k0 + r) * N + col + 0] : 0.f;
      v.y = (col + 1 < N) ? sp[(size_t)(k0 + r) * N + col + 1] : 0.f;
      v.z = (col + 2 < N) ? sp[(size_t)(k0 + r) * N + col + 2] : 0.f;
      v.w = 0.f;
    }
    S[r][tc + 0] = v.x; S[r][tc + 1] = v.y; S[r][tc + 2] = v.z; S[r][tc + 3] = v.w;
  }
  __syncthreads();
  #pragma unroll
  for (int it = 0; it < 4; ++it) {
    int rn = tr + it * 16;
    if (n0 + rn >= N) continue;
    u16 o[4];
    o[0] = f2bf(S[tc + 0][rn]); o[1] = f2bf(S[tc + 1][rn]);
    o[2] = f2bf(S[tc + 2][rn]); o[3] = f2bf(S[tc + 3][rn]);
    *(uint2*)&dp[(size_t)(n0 + rn) * K + k0 + tc] = *(uint2*)o;
  }
}

// six 1024x1024 transposes in one dispatch; z = which*4 + layer
struct TC6 { const float* src[6]; u16* dst[6]; size_t dstride[6]; };
__global__ __launch_bounds__(256) void k_tcast6(TC6 tc) {
  __shared__ float S[64][65];
  int w = blockIdx.z >> 2, l = blockIdx.z & 3;
  const float* sp = tc.src[w] + (size_t)l * 1024 * 1024;
  u16* dp = tc.dst[w] + (size_t)l * tc.dstride[w];
  int n0 = blockIdx.x * 64, k0 = blockIdx.y * 64;
  int tid = threadIdx.x;
  int tr = tid >> 4, tcc = (tid & 15) * 4;
  #pragma unroll
  for (int it = 0; it < 4; ++it) {
    int r = tr + it * 16;
    float4 v = *(const float4*)&sp[(size_t)(k0 + r) * 1024 + n0 + tcc];
    S[r][tcc + 0] = v.x; S[r][tcc + 1] = v.y; S[r][tcc + 2] = v.z; S[r][tcc + 3] = v.w;
  }
  __syncthreads();
  #pragma unroll
  for (int it = 0; it < 4; ++it) {
    int rn = tr + it * 16;
    u16 o[4];
    o[0] = f2bf(S[tcc + 0][rn]); o[1] = f2bf(S[tcc + 1][rn]);
    o[2] = f2bf(S[tcc + 2][rn]); o[3] = f2bf(S[tcc + 3][rn]);
    *(uint2*)&dp[(size_t)(n0 + rn) * 1024 + k0 + tcc] = *(uint2*)o;
  }
}

// ---------------- embed + rmsnorm fused ----------------
__global__ __launch_bounds__(256) void k_embln(const int* x, const float* embed,
                                               const float* w, float* h, u16* out) {
  __shared__ float sb[8];
  int t = blockIdx.x, tid = threadIdx.x;
  int row = x[t];
  float4 v = *(const float4*)&embed[(size_t)row * 1024 + tid * 4];
  *(float4*)&h[(size_t)t * 1024 + tid * 4] = v;
  float ss = v.x * v.x + v.y * v.y + v.z * v.z + v.w * v.w;
  float tot = block_sum(ss, sb);
  float rn = rsqrtf(tot / 1024.f + 1e-6f);
  int c = tid * 4;
  u16 o[4] = {f2bf(v.x * rn * w[c + 0]), f2bf(v.y * rn * w[c + 1]),
              f2bf(v.z * rn * w[c + 2]), f2bf(v.w * rn * w[c + 3])};
  *(uint2*)&out[(size_t)t * 1024 + c] = *(uint2*)o;
}

// ---------------- GEMM: counted-vmcnt dbuf, TH threads ----------------
enum { EPI_F32 = 0, EPI_QKV = 1, EPI_GELU = 2 };

struct GOut {
  void* out;
  const float* aux;
  size_t zstride;
  float *r, *k, *v, *ld, *g, *zx;
};

template <int EPI, int BM, int BN, int TH>
__global__ __launch_bounds__(TH) void k_gemm2(const u16* __restrict__ A,
                                              const u16* __restrict__ Bt,
                                              int N, int K, int kLen, GOut go) {
  __shared__ __align__(16) u16 smem[2][BM + BN][64];
  constexpr int NW = TH / 64;
  constexpr int NWM = (NW == 8) ? 4 : 2;
  constexpr int NWN = NW / NWM;
  constexpr int FR = BM / NWM / 16, FC = BN / NWN / 16;
  constexpr int ROWS = BM + BN;
  constexpr int RPW = ROWS / NW;          // rows per wave per stage
  constexpr int LPS = RPW / 8;            // gload16 per thread per stage
  int tid = threadIdx.x, lane = tid & 63, wid = tid >> 6;
  int lid = blockIdx.y * gridDim.x + blockIdx.x;
  int nwg = gridDim.x * gridDim.y;
  int q = nwg >> 3, r8 = nwg & 7;
  int xcd = lid & 7, pos = lid >> 3;
  int wg = (xcd < r8) ? (xcd * (q + 1) + pos) : (r8 * (q + 1) + (xcd - r8) * q + pos);
  int m0 = (wg % gridDim.x) * BM, n0 = (wg / gridDim.x) * BN;
  int kOff = blockIdx.z * kLen;
  int wr = (wid / NWN) * (BM / NWM), wc = (wid % NWN) * (BN / NWN);
  int lr = lane & 15, lk8 = (lane >> 4) * 8;
  int rsw = lr & 7;
  int swc = SWZ_SRC(lane);
  int rA = lane >> 3;
  f32x4 acc[FR][FC] = {};

  auto STAGE = [&](int buf, int k0) {
    #pragma unroll
    for (int it = 0; it < LPS; ++it) {
      int rb = wid * RPW + it * 8;
      if (rb < BM)
        gload16(&A[(size_t)(m0 + rb + rA) * K + k0 + swc], &smem[buf][rb][0]);
      else
        gload16(&Bt[(size_t)(n0 + rb - BM + rA) * K + k0 + swc], &smem[buf][rb][0]);
    }
  };
  auto COMPUTE = [&](int buf) {
    #pragma unroll
    for (int kb = 0; kb < 64; kb += 32) {
      s16x8 af[FR], bf[FC];
      #pragma unroll
      for (int i = 0; i < FR; ++i)
        af[i] = *(const s16x8*)&smem[buf][wr + i * 16 + lr][SWZ_RD(kb, lk8, rsw)];
      #pragma unroll
      for (int j = 0; j < FC; ++j)
        bf[j] = *(const s16x8*)&smem[buf][BM + wc + j * 16 + lr][SWZ_RD(kb, lk8, rsw)];
      #pragma unroll
      for (int i = 0; i < FR; ++i)
        #pragma unroll
        for (int j = 0; j < FC; ++j)
          acc[i][j] = __builtin_amdgcn_mfma_f32_16x16x32_bf16(af[i], bf[j], acc[i][j], 0, 0, 0);
    }
  };

  int nt = kLen >> 6;
  STAGE(0, kOff);
  int cur = 0;
  for (int t = 0; t < nt; ++t) {
    if (t + 1 < nt) {
      STAGE(cur ^ 1, kOff + (t + 1) * 64);
      asm volatile("s_waitcnt vmcnt(%0)" :: "n"(LPS) : "memory");
    } else {
      asm volatile("s_waitcnt vmcnt(0)" ::: "memory");
    }
    __builtin_amdgcn_s_barrier();
    __builtin_amdgcn_sched_barrier(0);
    COMPUTE(cur);
    __builtin_amdgcn_s_barrier();
    cur ^= 1;
  }

  if constexpr (EPI == EPI_F32) {
    // direct fragment stores (pure f32 streams)
    float* outf = (float*)go.out + (size_t)blockIdx.z * go.zstride;
    #pragma unroll
    for (int i = 0; i < FR; ++i)
      #pragma unroll
      for (int j = 0; j < FC; ++j) {
        int row = m0 + wr + i * 16 + ((lane >> 4) << 2);
        int col = n0 + wc + j * 16 + lr;
        if (col >= N) continue;
        #pragma unroll
        for (int r_ = 0; r_ < 4; ++r_)
          outf[(size_t)(row + r_) * N + col] = acc[i][j][r_];
      }
  } else {
    // LDS-transposed coalesced epilogue (branchy/down-converting targets)
    __syncthreads();
    float* cbuf = (float*)&smem[0][0][0];   // BM*BN*4 <= 2*(BM+BN)*64*2
    #pragma unroll
    for (int i = 0; i < FR; ++i)
      #pragma unroll
      for (int j = 0; j < FC; ++j) {
        int rrow = wr + i * 16 + ((lane >> 4) << 2);
        int ccol = wc + j * 16 + lr;
        #pragma unroll
        for (int r_ = 0; r_ < 4; ++r_)
          cbuf[(rrow + r_) * BN + ccol] = acc[i][j][r_];
      }
    __syncthreads();
    constexpr int RPB = BN / 4;
    constexpr int ITERS = (BM * RPB) / TH;
    if constexpr (EPI == EPI_GELU) {
      u16* outb = (u16*)go.out;
      #pragma unroll
      for (int it2 = 0; it2 < ITERS; ++it2) {
        int idx = it2 * TH + tid;
        int row = idx / RPB, c4 = (idx % RPB) * 4;
        int gc = n0 + c4;
        if (gc + 3 >= N) continue;
        float4 v = *(const float4*)&cbuf[row * BN + c4];
        u16 o[4];
        o[0] = f2bf(0.5f * v.x * (1.f + erff(v.x * 0.70710678118654752f)));
        o[1] = f2bf(0.5f * v.y * (1.f + erff(v.y * 0.70710678118654752f)));
        o[2] = f2bf(0.5f * v.z * (1.f + erff(v.z * 0.70710678118654752f)));
        o[3] = f2bf(0.5f * v.w * (1.f + erff(v.w * 0.70710678118654752f)));
        *(uint2*)&outb[(size_t)(m0 + row) * N + gc] = *(uint2*)o;
      }
    } else {  // EPI_QKV — uniform target per n-tile (tiles 1024-aligned)
      float* tptr; int ldbw, coff, op;
      if (n0 < 5120) {
        int tsel = n0 >> 10;
        tptr = (tsel == 0) ? go.r : (tsel == 1) ? go.k : (tsel == 2) ? go.v
             : (tsel == 3) ? go.ld : go.g;
        ldbw = 1024; coff = n0 & 1023;
        op = (tsel == 3) ? 1 : (tsel == 4) ? 2 : 0;
      } else {
        tptr = go.zx; ldbw = 4256; coff = n0 - 5120; op = 0;
      }
      #pragma unroll
      for (int it2 = 0; it2 < ITERS; ++it2) {
        int idx = it2 * TH + tid;
        int row = idx / RPB, c4 = (idx % RPB) * 4;
        int gc = n0 + c4;
        if (gc >= N) continue;
        float4 v = *(const float4*)&cbuf[row * BN + c4];
        float* pv = (float*)&v;
        if (op == 1) {
          #pragma unroll
          for (int e = 0; e < 4; ++e) pv[e] = -__expf(pv[e] + go.aux[coff + c4 + e]);
        } else if (op == 2) {
          #pragma unroll
          for (int e = 0; e < 4; ++e) pv[e] = pv[e] * sigf(pv[e]);
        }
        if (gc + 3 < N) *(float4*)&tptr[(size_t)(m0 + row) * ldbw + coff + c4] = v;
        else {
          for (int e = 0; e < 4 && gc + e < N; ++e)
            tptr[(size_t)(m0 + row) * ldbw + coff + c4 + e] = pv[e];
        }
      }
    }
  }
}

// ---------------- dual GEMM: z=0: og@Wo -> out_rwkv ; z=1: ymn@Wom -> out_mam ------
struct DualArg {
  const u16 *A0, *A1, *B0, *B1;
  float *o0, *o1;
  int K0, K1;
};
__global__ __launch_bounds__(256) void k_dual(DualArg da) {
  __shared__ __align__(16) u16 smem[2][128][64];
  const u16* A  = blockIdx.z ? da.A1 : da.A0;
  const u16* Bt = blockIdx.z ? da.B1 : da.B0;
  float* out    = blockIdx.z ? da.o1 : da.o0;
  int K         = blockIdx.z ? da.K1 : da.K0;
  const int N = 1024;
  int tid = threadIdx.x, lane = tid & 63, wid = tid >> 6;
  int lid = blockIdx.y * gridDim.x + blockIdx.x;
  int nwg = gridDim.x * gridDim.y;
  int q = nwg >> 3, r8 = nwg & 7;
  int xcd = lid & 7, pos = lid >> 3;
  int wg = (xcd < r8) ? (xcd * (q + 1) + pos) : (r8 * (q + 1) + (xcd - r8) * q + pos);
  int m0 = (wg % gridDim.x) * 64, n0 = (wg / gridDim.x) * 64;
  int wr = (wid >> 1) * 32, wc = (wid & 1) * 32;
  int lr = lane & 15, lk8 = (lane >> 4) * 8;
  int rsw = lr & 7, swc = SWZ_SRC(lane), rA = lane >> 3;
  f32x4 acc[2][2] = {};
  auto STAGE = [&](int buf, int k0) {
    #pragma unroll
    for (int it = 0; it < 2; ++it) {
      int rb = wid * 16 + it * 8;
      gload16(&A[(size_t)(m0 + rb + rA) * K + k0 + swc], &smem[buf][rb][0]);
      gload16(&Bt[(size_t)(n0 + rb + rA) * K + k0 + swc], &smem[buf][64 + rb][0]);
    }
  };
  auto COMPUTE = [&](int buf) {
    #pragma unroll
    for (int kb = 0; kb < 64; kb += 32) {
      s16x8 af[2], bf[2];
      #pragma unroll
      for (int i = 0; i < 2; ++i)
        af[i] = *(const s16x8*)&smem[buf][wr + i * 16 + lr][SWZ_RD(kb, lk8, rsw)];
      #pragma unroll
      for (int j = 0; j < 2; ++j)
        bf[j] = *(const s16x8*)&smem[buf][64 + wc + j * 16 + lr][SWZ_RD(kb, lk8, rsw)];
      #pragma unroll
      for (int i = 0; i < 2; ++i)
        #pragma unroll
        for (int j = 0; j < 2; ++j)
          acc[i][j] = __builtin_amdgcn_mfma_f32_16x16x32_bf16(af[i], bf[j], acc[i][j], 0, 0, 0);
    }
  };
  int nt = K >> 6;
  STAGE(0, 0);
  int cur = 0;
  for (int t = 0; t < nt; ++t) {
    if (t + 1 < nt) {
      STAGE(cur ^ 1, (t + 1) * 64);
      asm volatile("s_waitcnt vmcnt(4)" ::: "memory");
    } else {
      asm volatile("s_waitcnt vmcnt(0)" ::: "memory");
    }
    __builtin_amdgcn_s_barrier();
    __builtin_amdgcn_sched_barrier(0);
    COMPUTE(cur);
    __builtin_amdgcn_s_barrier();
    cur ^= 1;
  }
  __syncthreads();
  float* cbuf = (float*)&smem[0][0][0];
  #pragma unroll
  for (int i = 0; i < 2; ++i)
    #pragma unroll
    for (int j = 0; j < 2; ++j) {
      int rrow = wr + i * 16 + ((lane >> 4) << 2);
      int ccol = wc + j * 16 + lr;
      #pragma unroll
      for (int r_ = 0; r_ < 4; ++r_)
        cbuf[(rrow + r_) * 64 + ccol] = acc[i][j][r_];
    }
  __syncthreads();
  #pragma unroll
  for (int it2 = 0; it2 < 4; ++it2) {
    int idx = it2 * 256 + tid;
    int row = idx >> 4, c4 = (idx & 15) * 4;
    *(float4*)&out[(size_t)(m0 + row) * N + n0 + c4] = *(const float4*)&cbuf[row * 64 + c4];
  }
}

// ---------------- causal depthwise conv (K=4) + silu, 4 ch/thread ----------------
__global__ __launch_bounds__(256) void k_conv(const float* __restrict__ zx,
                                              const float* __restrict__ cw,
                                              float* __restrict__ xc) {
  int c = (blockIdx.x * 256 + threadIdx.x) * 4;
  int t = blockIdx.y;
  if (c >= CCONV) return;
  float4 w0 = *(const float4*)&cw[(c + 0) * 4];
  float4 w1 = *(const float4*)&cw[(c + 1) * 4];
  float4 w2 = *(const float4*)&cw[(c + 2) * 4];
  float4 w3 = *(const float4*)&cw[(c + 3) * 4];
  float4 a = {0.f, 0.f, 0.f, 0.f};
  #pragma unroll
  for (int tap = 0; tap < 4; ++tap) {
    int tt = t - 3 + tap;
    if (tt < 0) continue;
    float4 z = *(const float4*)&zx[(size_t)tt * NWIN + 2048 + c];
    a.x += z.x * ((const float*)&w0)[tap];
    a.y += z.y * ((const float*)&w1)[tap];
    a.z += z.z * ((const float*)&w2)[tap];
    a.w += z.w * ((const float*)&w3)[tap];
  }
  a.x = a.x * sigf(a.x); a.y = a.y * sigf(a.y);
  a.z = a.z * sigf(a.z); a.w = a.w * sigf(a.w);
  *(float4*)&xc[(size_t)t * CCONV + c] = a;
}

// ---------------- dtla (y=0) + bc quarters (y=1..4), per chunk ----------------
__global__ __launch_bounds__(256) void k_dtbc(const float* __restrict__ zx,
                                              const float* __restrict__ xc,
                                              const float* __restrict__ dt_bias,
                                              const float* __restrict__ A_log,
                                              float* __restrict__ dtb, float* __restrict__ la,
                                              float* __restrict__ BC) {
  int c = blockIdx.x, tid = threadIdx.x;
  if (blockIdx.y == 0) {
    __shared__ float ldaS[64][33];
    #pragma unroll
    for (int it = 0; it < 8; ++it) {
      int e = it * 256 + tid;
      int i = e >> 5, j = e & 31;
      float x = zx[(size_t)(c * 64 + i) * NWIN + 4224 + j] + dt_bias[j];
      float sp = (x > 20.f) ? x : log1pf(expf(x));
      dtb[(size_t)(c * 64 + i) * 32 + j] = sp;
      ldaS[i][j] = -sp * expf(A_log[j]);
    }
    __syncthreads();
    if (tid < 32) {
      float g = 0.f;
      for (int i = 0; i < 64; ++i) {
        g += ldaS[i][tid];
        la[((size_t)c * 32 + tid) * 64 + i] = g;
      }
    }
  } else {
    __shared__ float Bc[64][65];
    __shared__ float Cc[16][65];
    int i0 = (blockIdx.y - 1) * 16;
    #pragma unroll
    for (int it = 0; it < 4; ++it) {
      int idx = it * 256 + tid;
      int r = idx >> 4, c4 = (idx & 15) * 4;
      float4 b4 = *(const float4*)&xc[(size_t)(c * 64 + r) * CCONV + 2048 + c4];
      Bc[r][c4] = b4.x; Bc[r][c4+1] = b4.y; Bc[r][c4+2] = b4.z; Bc[r][c4+3] = b4.w;
    }
    {
      int r = tid >> 4, c4 = (tid & 15) * 4;
      float4 cv = *(const float4*)&xc[(size_t)(c * 64 + i0 + r) * CCONV + 2112 + c4];
      Cc[r][c4] = cv.x; Cc[r][c4+1] = cv.y; Cc[r][c4+2] = cv.z; Cc[r][c4+3] = cv.w;
    }
    __syncthreads();
    int il = tid >> 4, sg = tid & 15;
    float acc[4] = {};
    for (int d = 0; d < 64; ++d) {
      float cv = Cc[il][d];
      #pragma unroll
      for (int j = 0; j < 4; ++j) acc[j] += Bc[sg * 4 + j][d] * cv;
    }
    #pragma unroll
    for (int j = 0; j < 4; ++j)
      BC[((size_t)c * 64 + i0 + il) * 64 + sg * 4 + j] = acc[j];
  }
}

// ---------------- heads1: rwkvA (y<16) || mambaU (y>=16) ----------------
union SmemH1 {
  struct { float rS[64][66], kS[64][66], gS[64][66]; u16 khS[64][64]; u16 vtS[64][72]; float uS[64]; } a;
  struct { u16 XT[64][72], BT[64][72]; float fS[64]; } b;
};
__global__ __launch_bounds__(256) void k_heads1(const float* __restrict__ rbuf,
                                                const float* __restrict__ kbuf,
                                                const float* __restrict__ ldbuf,
                                                const float* __restrict__ vbuf,
                                                const float* __restrict__ u,
                                                const float* __restrict__ xc,
                                                const float* __restrict__ la,
                                                const float* __restrict__ dtb,
                                                u16* __restrict__ rt, float* __restrict__ eL,
                                                u16* __restrict__ G, float* __restrict__ U,
                                                float* __restrict__ Um) {
  __shared__ SmemH1 sm;
  int c = blockIdx.x, tid = threadIdx.x;
  int lane = tid & 63, wid = tid >> 6;
  int lr = lane & 15, lk8 = (lane >> 4) * 8, rsw = lr & 7;
  int wr = (wid >> 1) * 32, wc = (wid & 1) * 32;
  if (blockIdx.y < 16) {
    int h = blockIdx.y;
    #pragma unroll
    for (int it = 0; it < 4; ++it) {
      int idx = it * 256 + tid;
      int i = idx >> 4, c4 = (idx & 15) * 4;
      size_t base = (size_t)(c * 64 + i) * 1024 + h * 64 + c4;
      float4 rv = *(const float4*)&rbuf[base];
      float4 kv = *(const float4*)&kbuf[base];
      float4 lv = *(const float4*)&ldbuf[base];
      float4 vv = *(const float4*)&vbuf[base];
      sm.a.rS[i][c4] = rv.x; sm.a.rS[i][c4+1] = rv.y; sm.a.rS[i][c4+2] = rv.z; sm.a.rS[i][c4+3] = rv.w;
      sm.a.kS[i][c4] = kv.x; sm.a.kS[i][c4+1] = kv.y; sm.a.kS[i][c4+2] = kv.z; sm.a.kS[i][c4+3] = kv.w;
      sm.a.gS[i][c4] = lv.x; sm.a.gS[i][c4+1] = lv.y; sm.a.gS[i][c4+2] = lv.z; sm.a.gS[i][c4+3] = lv.w;
      sm.a.vtS[c4 + 0][i] = f2bf(vv.x); sm.a.vtS[c4 + 1][i] = f2bf(vv.y);
      sm.a.vtS[c4 + 2][i] = f2bf(vv.z); sm.a.vtS[c4 + 3][i] = f2bf(vv.w);
    }
    if (tid < 64) sm.a.uS[tid] = u[h * 64 + tid];
    __syncthreads();
    if (tid < 64) {
      int k = tid;
      float g = 0.f;
      for (int i = 0; i < 64; ++i) {
        float ld = sm.a.gS[i][k];
        sm.a.gS[i][k] = g;
        rt[(size_t)(c * 64 + i) * 1024 + h * 64 + k] = f2bf(sm.a.rS[i][k] * __expf(g));
        g += ld;
      }
      float gL = g;
      eL[((size_t)c * 16 + h) * 64 + k] = __expf(gL);
      for (int i = 0; i < 64; ++i) {
        float gincl = (i < 63) ? sm.a.gS[i + 1][k] : gL;
        int col = (((i >> 3) ^ (k & 7)) << 3) | (i & 7);
        sm.a.khS[k][col] = f2bf(sm.a.kS[i][k] * __expf(fminf(gL - gincl, 0.f)));
      }
    }
    __syncthreads();
    {
      int i = tid & 63, sg = tid >> 6;
      float acc[16] = {};
      float accd = 0.f;
      for (int k = 0; k < 64; ++k) {
        float rv = sm.a.rS[i][k], gi = sm.a.gS[i][k];
        accd += rv * sm.a.uS[k] * sm.a.kS[i][k];
        #pragma unroll
        for (int j = 0; j < 16; ++j) {
          int s = sg * 16 + j;
          int sp1 = (s < 63) ? s + 1 : 63;
          acc[j] += rv * sm.a.kS[s][k] * __expf(fminf(gi - sm.a.gS[sp1][k], 0.f));
        }
      }
      #pragma unroll
      for (int j = 0; j < 16; ++j) {
        int s = sg * 16 + j;
        float v = (s < i) ? acc[j] : ((s == i) ? accd : 0.f);
        G[(((size_t)c * 16 + h) * 64 + i) * 64 + s] = f2bf(v);
      }
    }
    {
      size_t gb = ((size_t)c * 16 + h) * 64;
      f32x4 acc2[2][2] = {};
      #pragma unroll
      for (int kb = 0; kb < 64; kb += 32) {
        s16x8 a[2], b[2];
        #pragma unroll
        for (int i_ = 0; i_ < 2; ++i_)
          a[i_] = *(const s16x8*)&sm.a.khS[wr + i_ * 16 + lr][SWZ_RD(kb, lk8, rsw)];
        #pragma unroll
        for (int j_ = 0; j_ < 2; ++j_)
          b[j_] = *(const s16x8*)&sm.a.vtS[wc + j_ * 16 + lr][kb + lk8];
        #pragma unroll
        for (int i_ = 0; i_ < 2; ++i_)
          #pragma unroll
          for (int j_ = 0; j_ < 2; ++j_)
            acc2[i_][j_] = __builtin_amdgcn_mfma_f32_16x16x32_bf16(a[i_], b[j_], acc2[i_][j_], 0, 0, 0);
      }
      #pragma unroll
      for (int i_ = 0; i_ < 2; ++i_)
        #pragma unroll
        for (int j_ = 0; j_ < 2; ++j_) {
          int row = wr + i_ * 16 + ((lane >> 4) << 2);
          int col = wc + j_ * 16 + lr;
          #pragma unroll
          for (int r_ = 0; r_ < 4; ++r_)
            U[(gb + row + r_) * 64 + col] = acc2[i_][j_][r_];
        }
    }
  } else {
    int h = blockIdx.y - 16;
    size_t lb = ((size_t)c * 32 + h) * 64;
    if (tid < 64) {
      float la63 = la[lb + 63];
      sm.b.fS[tid] = dtb[(size_t)(c * 64 + tid) * 32 + h] * __expf(fminf(la63 - la[lb + tid], 0.f));
    }
    __syncthreads();
    #pragma unroll
    for (int it = 0; it < 4; ++it) {
      int idx = it * 256 + tid;
      int t = idx >> 4, p4 = (idx & 15) * 4;
      float f = sm.b.fS[t];
      float4 xv = *(const float4*)&xc[(size_t)(c * 64 + t) * CCONV + h * 64 + p4];
      sm.b.XT[p4 + 0][t] = f2bf(f * xv.x); sm.b.XT[p4 + 1][t] = f2bf(f * xv.y);
      sm.b.XT[p4 + 2][t] = f2bf(f * xv.z); sm.b.XT[p4 + 3][t] = f2bf(f * xv.w);
      float4 bv = *(const float4*)&xc[(size_t)(c * 64 + t) * CCONV + 2048 + p4];
      sm.b.BT[p4 + 0][t] = f2bf(bv.x); sm.b.BT[p4 + 1][t] = f2bf(bv.y);
      sm.b.BT[p4 + 2][t] = f2bf(bv.z); sm.b.BT[p4 + 3][t] = f2bf(bv.w);
    }
    __syncthreads();
    f32x4 acc[2][2] = {};
    #pragma unroll
    for (int kb = 0; kb < 64; kb += 32) {
      s16x8 a[2], b[2];
      #pragma unroll
      for (int i = 0; i < 2; ++i) a[i] = *(const s16x8*)&sm.b.XT[wr + i * 16 + lr][kb + lk8];
      #pragma unroll
      for (int j = 0; j < 2; ++j) b[j] = *(const s16x8*)&sm.b.BT[wc + j * 16 + lr][kb + lk8];
      #pragma unroll
      for (int i = 0; i < 2; ++i)
        #pragma unroll
        for (int j = 0; j < 2; ++j)
          acc[i][j] = __builtin_amdgcn_mfma_f32_16x16x32_bf16(a[i], b[j], acc[i][j], 0, 0, 0);
    }
    #pragma unroll
    for (int i = 0; i < 2; ++i)
      #pragma unroll
      for (int j = 0; j < 2; ++j) {
        int row = wr + i * 16 + ((lane >> 4) << 2);
        int col = wc + j * 16 + lr;
        #pragma unroll
        for (int r_ = 0; r_ < 4; ++r_)
          Um[(lb + row + r_) * 64 + col] = acc[i][j][r_];
      }
  }
}

// ---------------- scan2: rwkv (x<16) || mamba (x>=16) ----------------
__global__ __launch_bounds__(256) void k_scan2(const float* __restrict__ Urw,
                                               const float* __restrict__ eL,
                                               u16* __restrict__ Sall,
                                               const float* __restrict__ Um,
                                               const float* __restrict__ la,
                                               u16* __restrict__ hall) {
  int tid = threadIdx.x;
  if (blockIdx.x < 16) {
    int h = blockIdx.x;
    int k = tid >> 2, v0 = blockIdx.y * 16 + (tid & 3) * 4;
    float S[4] = {};
    for (int c = 0; c < 16; ++c) {
      size_t gb = ((size_t)c * 16 + h) * 64;
      u16 tmp[4] = {f2bf(S[0]), f2bf(S[1]), f2bf(S[2]), f2bf(S[3])};
      *(uint2*)&Sall[(gb + k) * 64 + v0] = *(uint2*)&tmp[0];
      float e = eL[gb + k];
      float4 uv = *(const float4*)&Urw[(gb + k) * 64 + v0];
      S[0] = e * S[0] + uv.x; S[1] = e * S[1] + uv.y;
      S[2] = e * S[2] + uv.z; S[3] = e * S[3] + uv.w;
    }
  } else {
    int h = blockIdx.x - 16;
    int p = tid >> 2, s0 = blockIdx.y * 16 + (tid & 3) * 4;
    float S[4] = {};
    for (int c = 0; c < 16; ++c) {
      size_t lb = ((size_t)c * 32 + h) * 64;
      u16 tmp[4] = {f2bf(S[0]), f2bf(S[1]), f2bf(S[2]), f2bf(S[3])};
      *(uint2*)&hall[(lb + p) * 64 + s0] = *(uint2*)&tmp[0];
      float e = __expf(la[lb + 63]);
      float4 uv = *(const float4*)&Um[(lb + p) * 64 + s0];
      S[0] = e * S[0] + uv.x; S[1] = e * S[1] + uv.y;
      S[2] = e * S[2] + uv.z; S[3] = e * S[3] + uv.w;
    }
  }
}

// ---------------- heads2: rwkvO (y<16) || mambaY w/ inline M (y>=16) ----------------
union SmemH2 {
  struct { u16 rtS[64][64], GS[64][64], StS[64][72], vtS[64][72]; } a;
  struct { u16 MS[64][64], hS[64][64], CtS[64][72], XT2[64][72]; float laS[64], dtbS[64], eS[64]; } b;
};
__global__ __launch_bounds__(256) void k_heads2(const u16* __restrict__ rt,
                                                const u16* __restrict__ Gb,
                                                const u16* __restrict__ Sall,
                                                const float* __restrict__ vbuf,
                                                const float* __restrict__ gbuf,
                                                u16* __restrict__ og,
                                                const u16* __restrict__ hall,
                                                const float* __restrict__ xc,
                                                const float* __restrict__ la,
                                                const float* __restrict__ dtb,
                                                const float* __restrict__ BC,
                                                float* __restrict__ ymb) {
  __shared__ SmemH2 sm;
  int c = blockIdx.x, tid = threadIdx.x;
  int lane = tid & 63, wid = tid >> 6;
  int lr = lane & 15, lk8 = (lane >> 4) * 8;
  int rsw = lr & 7, swc = SWZ_SRC(lane);
  int wr = (wid >> 1) * 32, wc = (wid & 1) * 32;
  if (blockIdx.y < 16) {
    int h = blockIdx.y;
    size_t gb = ((size_t)c * 16 + h) * 64;
    #pragma unroll
    for (int it = 0; it < 2; ++it) {
      int rb = wid * 16 + it * 8;
      int r = rb + (lane >> 3);
      gload16(&rt[(size_t)(c * 64 + r) * 1024 + h * 64 + swc], &sm.a.rtS[rb][0]);
      gload16(&Gb[(gb + r) * 64 + swc], &sm.a.GS[rb][0]);
    }
    #pragma unroll
    for (int it = 0; it < 2; ++it) {
      int idx = it * 256 + tid;
      int k = idx >> 3, c8 = (idx & 7) * 8;
      uint4 ld = *(const uint4*)&Sall[(gb + k) * 64 + c8];
      const u16* pv = (const u16*)&ld;
      #pragma unroll
      for (int jj = 0; jj < 8; ++jj) sm.a.StS[c8 + jj][k] = pv[jj];
    }
    #pragma unroll
    for (int it = 0; it < 4; ++it) {
      int idx = it * 256 + tid;
      int s = idx >> 4, v4 = (idx & 15) * 4;
      float4 vv = *(const float4*)&vbuf[(size_t)(c * 64 + s) * 1024 + h * 64 + v4];
      sm.a.vtS[v4 + 0][s] = f2bf(vv.x); sm.a.vtS[v4 + 1][s] = f2bf(vv.y);
      sm.a.vtS[v4 + 2][s] = f2bf(vv.z); sm.a.vtS[v4 + 3][s] = f2bf(vv.w);
    }
    __syncthreads();
    f32x4 acc[2][2] = {};
    #pragma unroll
    for (int kb = 0; kb < 64; kb += 32) {
      s16x8 aR[2], aG[2], bS[2], bV[2];
      #pragma unroll
      for (int i = 0; i < 2; ++i) {
        aR[i] = *(const s16x8*)&sm.a.rtS[wr + i * 16 + lr][SWZ_RD(kb, lk8, rsw)];
        aG[i] = *(const s16x8*)&sm.a.GS[wr + i * 16 + lr][SWZ_RD(kb, lk8, rsw)];
      }
      #pragma unroll
      for (int j = 0; j < 2; ++j) {
        bS[j] = *(const s16x8*)&sm.a.StS[wc + j * 16 + lr][kb + lk8];
        bV[j] = *(const s16x8*)&sm.a.vtS[wc + j * 16 + lr][kb + lk8];
      }
      #pragma unroll
      for (int i = 0; i < 2; ++i)
        #pragma unroll
        for (int j = 0; j < 2; ++j) {
          acc[i][j] = __builtin_amdgcn_mfma_f32_16x16x32_bf16(aR[i], bS[j], acc[i][j], 0, 0, 0);
          acc[i][j] = __builtin_amdgcn_mfma_f32_16x16x32_bf16(aG[i], bV[j], acc[i][j], 0, 0, 0);
        }
    }
    #pragma unroll
    for (int i = 0; i < 2; ++i)
      #pragma unroll
      for (int j = 0; j < 2; ++j) {
        int row = c * 64 + wr + i * 16 + ((lane >> 4) << 2);
        int col = h * 64 + wc + j * 16 + lr;
        #pragma unroll
        for (int r_ = 0; r_ < 4; ++r_) {
          size_t idx = (size_t)(row + r_) * 1024 + col;
          og[idx] = f2bf(acc[i][j][r_] * gbuf[idx]);
        }
      }
  } else {
    int h = blockIdx.y - 16;
    size_t lb = ((size_t)c * 32 + h) * 64;
    if (tid < 64) {
      float lv = la[lb + tid];
      sm.b.laS[tid] = lv;
      sm.b.eS[tid] = __expf(lv);
      sm.b.dtbS[tid] = dtb[(size_t)(c * 64 + tid) * 32 + h];
    }
    #pragma unroll
    for (int it = 0; it < 2; ++it) {
      int rb = wid * 16 + it * 8;
      int r = rb + (lane >> 3);
      gload16(&hall[(lb + r) * 64 + swc], &sm.b.hS[rb][0]);
    }
    __syncthreads();
    #pragma unroll
    for (int it = 0; it < 4; ++it) {
      int idx = it * 256 + tid;
      int i = idx >> 4, s4 = (idx & 15) * 4;
      float lai = sm.b.laS[i];
      float4 bc4 = *(const float4*)&BC[((size_t)c * 64 + i) * 64 + s4];
      u16 mo[4];
      #pragma unroll
      for (int j = 0; j < 4; ++j) {
        int s = s4 + j;
        float bcv = (j == 0) ? bc4.x : (j == 1) ? bc4.y : (j == 2) ? bc4.z : bc4.w;
        float v = 0.f;
        if (s <= i)
          v = __expf(fminf(lai - sm.b.laS[s], 0.f)) * sm.b.dtbS[s] * bcv;
        mo[j] = f2bf(v);
      }
      *(uint2*)&sm.b.MS[i][(((s4 >> 3) ^ (i & 7)) << 3) | (s4 & 7)] = *(uint2*)mo;
      float ei = sm.b.eS[i];
      float4 cv = *(const float4*)&xc[(size_t)(c * 64 + i) * CCONV + 2112 + s4];
      sm.b.CtS[i][s4 + 0] = f2bf(ei * cv.x); sm.b.CtS[i][s4 + 1] = f2bf(ei * cv.y);
      sm.b.CtS[i][s4 + 2] = f2bf(ei * cv.z); sm.b.CtS[i][s4 + 3] = f2bf(ei * cv.w);
      float4 xv = *(const float4*)&xc[(size_t)(c * 64 + i) * CCONV + h * 64 + s4];
      sm.b.XT2[s4 + 0][i] = f2bf(xv.x); sm.b.XT2[s4 + 1][i] = f2bf(xv.y);
      sm.b.XT2[s4 + 2][i] = f2bf(xv.z); sm.b.XT2[s4 + 3][i] = f2bf(xv.w);
    }
    __syncthreads();
    f32x4 acc[2][2] = {};
    #pragma unroll
    for (int kb = 0; kb < 64; kb += 32) {
      s16x8 aM[2], aC[2], bX[2], bH[2];
      #pragma unroll
      for (int i = 0; i < 2; ++i) {
        aM[i] = *(const s16x8*)&sm.b.MS[wr + i * 16 + lr][SWZ_RD(kb, lk8, rsw)];
        aC[i] = *(const s16x8*)&sm.b.CtS[wr + i * 16 + lr][kb + lk8];
      }
      #pragma unroll
      for (int j = 0; j < 2; ++j) {
        bX[j] = *(const s16x8*)&sm.b.XT2[wc + j * 16 + lr][kb + lk8];
        bH[j] = *(const s16x8*)&sm.b.hS[wc + j * 16 + lr][SWZ_RD(kb, lk8, rsw)];
      }
      #pragma unroll
      for (int i = 0; i < 2; ++i)
        #pragma unroll
        for (int j = 0; j < 2; ++j) {
          acc[i][j] = __builtin_amdgcn_mfma_f32_16x16x32_bf16(aM[i], bX[j], acc[i][j], 0, 0, 0);
          acc[i][j] = __builtin_amdgcn_mfma_f32_16x16x32_bf16(aC[i], bH[j], acc[i][j], 0, 0, 0);
        }
    }
    #pragma unroll
    for (int i = 0; i < 2; ++i)
      #pragma unroll
      for (int j = 0; j < 2; ++j) {
        int row = c * 64 + wr + i * 16 + ((lane >> 4) << 2);
        int col = h * 64 + wc + j * 16 + lr;
        #pragma unroll
        for (int r_ = 0; r_ < 4; ++r_)
          ymb[(size_t)(row + r_) * 2048 + col] = acc[i][j][r_];
      }
  }
}

// ---------------- ym: +Dskip*x, *silu(z), rmsnorm(2048) -> bf16 ----------------
__global__ __launch_bounds__(256) void k_ymn(const float* ymb, const float* xc,
                                             const float* zx, const float* Dsk,
                                             const float* mnw, u16* out) {
  __shared__ float sb[8];
  int t = blockIdx.x, tid = threadIdx.x;
  float vals[8];
  float ss = 0.f;
  #pragma unroll
  for (int j = 0; j < 8; ++j) {
    int cidx = j * 256 + tid;
    float yv = ymb[(size_t)t * 2048 + cidx] + Dsk[cidx >> 6] * xc[(size_t)t * CCONV + cidx];
    float zv = zx[(size_t)t * NWIN + cidx];
    float val = yv * zv * sigf(zv);
    vals[j] = val;
    ss += val * val;
  }
  float tot = block_sum(ss, sb);
  float rn = rsqrtf(tot / 2048.f + 1e-6f);
  #pragma unroll
  for (int j = 0; j < 8; ++j) {
    int cidx = j * 256 + tid;
    out[(size_t)t * 2048 + cidx] = f2bf(vals[j] * rn * mnw[cidx]);
  }
}

// ---------------- gate + residual + ffn rmsnorm (fused) ----------------
__global__ __launch_bounds__(256) void k_gateln(const float* rw, const float* mb,
                                                const float* gw, const float* gb,
                                                float* h, const float* w, u16* nx) {
  __shared__ float sb[8];
  int t = blockIdx.x, tid = threadIdx.x;
  float s = 0.f;
  #pragma unroll
  for (int j = 0; j < 4; ++j) {
    int d = j * 256 + tid;
    s += rw[(size_t)t * 1024 + d] * gw[d] + mb[(size_t)t * 1024 + d] * gw[1024 + d];
  }
  float tot = block_sum(s, sb);
  float gate = sigf(tot + gb[0]);
  float hv[4], ss = 0.f;
  #pragma unroll
  for (int j = 0; j < 4; ++j) {
    int d = j * 256 + tid;
    float v = h[(size_t)t * 1024 + d] + gate * rw[(size_t)t * 1024 + d] +
              (1.f - gate) * mb[(size_t)t * 1024 + d];
    h[(size_t)t * 1024 + d] = v;
    hv[j] = v;
    ss += v * v;
  }
  float tot2 = block_sum(ss, sb);
  float rn = rsqrtf(tot2 / 1024.f + 1e-6f);
  #pragma unroll
  for (int j = 0; j < 4; ++j) {
    int d = j * 256 + tid;
    nx[(size_t)t * 1024 + d] = f2bf(hv[j] * rn * w[d]);
  }
}

// ---------------- W2 splitK reduce + h += + next rmsnorm (fused) ----------------
__global__ __launch_bounds__(256) void k_redln(const float* __restrict__ part,
                                               float* __restrict__ h,
                                               const float* __restrict__ w,
                                               u16* __restrict__ nx) {
  __shared__ float sb[8];
  int t = blockIdx.x, tid = threadIdx.x;
  size_t base = (size_t)t * 1024 + tid * 4;
  float4 s = *(const float4*)&part[base];
  #pragma unroll
  for (int p = 1; p < 4; ++p) {
    float4 v = *(const float4*)&part[(size_t)p * 1024 * 1024 + base];
    s.x += v.x; s.y += v.y; s.z += v.z; s.w += v.w;
  }
  float4 d = *(const float4*)&h[base];
  s.x += d.x; s.y += d.y; s.z += d.z; s.w += d.w;
  *(float4*)&h[base] = s;
  float ss = s.x * s.x + s.y * s.y + s.z * s.z + s.w * s.w;
  float tot = block_sum(ss, sb);
  float rn = rsqrtf(tot / 1024.f + 1e-6f);
  int c = tid * 4;
  u16 o[4] = {f2bf(s.x * rn * w[c + 0]), f2bf(s.y * rn * w[c + 1]),
              f2bf(s.z * rn * w[c + 2]), f2bf(s.w * rn * w[c + 3])};
  *(uint2*)&nx[(size_t)t * 1024 + c] = *(uint2*)o;
}

// =======================================================================
extern "C" void kernel_launch(void* const* d_in, const int* in_sizes, int n_in,
                              void* d_out, int out_size, void* d_ws, size_t ws_size,
                              hipStream_t stream) {
  const int*   x       = (const int*)d_in[0];
  const float* embed   = (const float*)d_in[1];
  const float* ln_w    = (const float*)d_in[2];
  const float* Wr      = (const float*)d_in[3];
  const float* Wk      = (const float*)d_in[4];
  const float* Wv      = (const float*)d_in[5];
  const float* Ww      = (const float*)d_in[6];
  const float* w_bias  = (const float*)d_in[7];
  const float* u       = (const float*)d_in[8];
  const float* Wg      = (const float*)d_in[9];
  const float* Wo      = (const float*)d_in[10];
  const float* Win     = (const float*)d_in[11];
  const float* conv_w  = (const float*)d_in[12];
  const float* dt_bias = (const float*)d_in[13];
  const float* A_log   = (const float*)d_in[14];
  const float* Dskip   = (const float*)d_in[15];
  const float* mnorm_w = (const float*)d_in[16];
  const float* Wout_m  = (const float*)d_in[17];
  const float* gate_w  = (const float*)d_in[18];
  const float* gate_b  = (const float*)d_in[19];
  const float* ffn_ln  = (const float*)d_in[20];
  const float* W1      = (const float*)d_in[21];
  const float* W2      = (const float*)d_in[22];
  const float* ln_out  = (const float*)d_in[23];

  char* p = (char*)d_ws;
  auto alloc = [&](size_t bytes) {
    char* r = p;
    p += (bytes + 255) & ~(size_t)255;
    return r;
  };
  u16* embB = (u16*)alloc((size_t)VOCABSZ * 1024 * 2);
  u16* Wpk  = (u16*)alloc((size_t)NLAYER * PKROWS * 1024 * 2);
  u16* WoT  = (u16*)alloc((size_t)NLAYER * 1024 * 1024 * 2);
  u16* WomT = (u16*)alloc((size_t)NLAYER * 1024 * 2048 * 2);
  u16* W1T  = (u16*)alloc((size_t)NLAYER * 4096 * 1024 * 2);
  u16* W2T  = (u16*)alloc((size_t)NLAYER * 1024 * 4096 * 2);
  float* h        = (float*)alloc((size_t)T * 1024 * 4);
  u16*   nx       = (u16*)alloc((size_t)T * 1024 * 2);
  float* rbuf     = (float*)alloc((size_t)T * 1024 * 4);
  float* kbuf     = (float*)alloc((size_t)T * 1024 * 4);
  float* vbuf     = (float*)alloc((size_t)T * 1024 * 4);
  float* ldbuf    = (float*)alloc((size_t)T * 1024 * 4);
  float* gbuf     = (float*)alloc((size_t)T * 1024 * 4);
  float* zx       = (float*)alloc((size_t)T * NWIN * 4);
  u16*   rt       = (u16*)alloc((size_t)T * 1024 * 2);
  float* eL       = (float*)alloc((size_t)NCHUNK * 16 * 64 * 4);
  u16*   Gb       = (u16*)alloc((size_t)NCHUNK * 16 * 64 * 64 * 2);
  float* Urw      = (float*)alloc((size_t)NCHUNK * 16 * 64 * 64 * 4);
  u16*   Sall     = (u16*)alloc((size_t)NCHUNK * 16 * 64 * 64 * 2);
  u16*   og       = (u16*)alloc((size_t)T * 1024 * 2);
  float* out_rwkv = (float*)alloc((size_t)T * 1024 * 4);
  float* xc       = (float*)alloc((size_t)T * CCONV * 4);
  float* dtb      = (float*)alloc((size_t)T * 32 * 4);
  float* la       = (float*)alloc((size_t)NCHUNK * 32 * 64 * 4);
  float* BC       = (float*)alloc((size_t)NCHUNK * 64 * 64 * 4);
  float* Um       = (float*)alloc((size_t)NCHUNK * 32 * 64 * 64 * 4);
  u16*   hall     = (u16*)alloc((size_t)NCHUNK * 32 * 64 * 64 * 2);
  float* ymb      = (float*)alloc((size_t)T * 2048 * 4);
  u16*   ymn      = (u16*)alloc((size_t)T * 2048 * 2);
  float* out_mam  = (float*)alloc((size_t)T * 1024 * 4);
  u16*   ffa      = (u16*)alloc((size_t)T * FFH * 2);
  float* part     = (float*)alloc((size_t)4 * 1024 * 1024 * 4);

  const size_t PKS = (size_t)PKROWS * 1024;

  // ---- weight conversion ----
  k_cast<<<VOCABSZ * 1024 / 1024, 256, 0, stream>>>(embed, embB);
  {
    TC6 tc;
    tc.src[0] = Wr; tc.src[1] = Wk; tc.src[2] = Wv; tc.src[3] = Ww; tc.src[4] = Wg; tc.src[5] = Wo;
    tc.dst[0] = Wpk;               tc.dstride[0] = PKS;
    tc.dst[1] = Wpk + 1024 * 1024; tc.dstride[1] = PKS;
    tc.dst[2] = Wpk + 2048 * 1024; tc.dstride[2] = PKS;
    tc.dst[3] = Wpk + 3072 * 1024; tc.dstride[3] = PKS;
    tc.dst[4] = Wpk + 4096 * 1024; tc.dstride[4] = PKS;
    tc.dst[5] = WoT;               tc.dstride[5] = (size_t)1024 * 1024;
    k_tcast6<<<dim3(16, 16, 24), 256, 0, stream>>>(tc);
  }
  k_tcast<<<dim3(67, 16, 4), 256, 0, stream>>>(Win, (size_t)1024 * NWIN, Wpk + (size_t)5120 * 1024, PKS, 1024, NWIN);
  k_tcast<<<dim3(16, 32, 4), 256, 0, stream>>>(Wout_m, (size_t)2048 * 1024, WomT, (size_t)1024 * 2048, 2048, 1024);
  k_tcast<<<dim3(64, 16, 4), 256, 0, stream>>>(W1, (size_t)1024 * 4096, W1T, (size_t)4096 * 1024, 1024, 4096);
  k_tcast<<<dim3(16, 64, 4), 256, 0, stream>>>(W2, (size_t)4096 * 1024, W2T, (size_t)1024 * 4096, 4096, 1024);

  k_embln<<<1024, 256, 0, stream>>>(x, embed, ln_w, h, nx);

  for (int l = 0; l < NLAYER; ++l) {
    {
      GOut go = {};
      go.r = rbuf; go.k = kbuf; go.v = vbuf; go.ld = ldbuf; go.g = gbuf; go.zx = zx;
      go.aux = w_bias + l * 1024;
      k_gemm2<EPI_QKV, 128, 128, 512><<<dim3(8, 74), 512, 0, stream>>>(nx, Wpk + (size_t)l * PKS, PKN, 1024, 1024, go);
    }
    k_conv<<<dim3(3, 1024), 256, 0, stream>>>(zx, conv_w + (size_t)l * CCONV * 4, xc);
    k_dtbc<<<dim3(16, 5), 256, 0, stream>>>(zx, xc, dt_bias + l * 32, A_log + l * 32, dtb, la, BC);
    k_heads1<<<dim3(16, 48), 256, 0, stream>>>(rbuf, kbuf, ldbuf, vbuf, u + (size_t)l * 1024,
                                               xc, la, dtb, rt, eL, Gb, Urw, Um);
    k_scan2<<<dim3(48, 4), 256, 0, stream>>>(Urw, eL, Sall, Um, la, hall);
    k_heads2<<<dim3(16, 48), 256, 0, stream>>>(rt, Gb, Sall, vbuf, gbuf, og,
                                               hall, xc, la, dtb, BC, ymb);
    k_ymn<<<1024, 256, 0, stream>>>(ymb, xc, zx, Dskip + l * 32, mnorm_w + (size_t)l * 2048, ymn);
    {
      DualArg da;
      da.A0 = og;  da.B0 = WoT + (size_t)l * 1024 * 1024;  da.o0 = out_rwkv; da.K0 = 1024;
      da.A1 = ymn; da.B1 = WomT + (size_t)l * 1024 * 2048; da.o1 = out_mam;  da.K1 = 2048;
      k_dual<<<dim3(16, 16, 2), 256, 0, stream>>>(da);
    }
    k_gateln<<<1024, 256, 0, stream>>>(out_rwkv, out_mam, gate_w + (size_t)l * 2048,
                                       gate_b + l, h, ffn_ln + l * 1024, nx);
    {
      GOut go = {}; go.out = ffa;
      k_gemm2<EPI_GELU, 128, 128, 512><<<dim3(8, 32), 512, 0, stream>>>(nx, W1T + (size_t)l * 4096 * 1024, 4096, 1024, 1024, go);
    }
    {
      GOut go = {}; go.out = part; go.zstride = (size_t)1024 * 1024;
      k_gemm2<EPI_F32, 64, 64, 256><<<dim3(16, 16, 4), 256, 0, stream>>>(ffa, W2T + (size_t)l * 1024 * 4096, 1024, 4096, 1024, go);
    }
    k_redln<<<1024, 256, 0, stream>>>(part, h,
                                      (l < NLAYER - 1) ? (ln_w + (l + 1) * 1024) : ln_out, nx);
  }

  {
    GOut go = {}; go.out = d_out;
    k_gemm2<EPI_F32, 128, 128, 512><<<dim3(8, 250), 512, 0, stream>>>(nx, embB, VOCABSZ, 1024, 1024, go);
  }
}